// Round 1
// baseline (4665.535 us; speedup 1.0000x reference)
//
#include <hip/hip_runtime.h>
#include <math.h>

#define KD 64
#define NR 128
#define NMAT 3
#define NDF 6
#define NITER 15
#define TPB 512
#define BPB 8
#define MPAD 68
#define NBATCH 4096
#define PI_F 3.14159265358979323846f
#define RHO_F 1.0f

// LDS float counts / offsets
#define OFF_ML   0
#define SZ_ML    (NMAT*NR*MPAD)        // 26112
#define OFF_WV   (OFF_ML + SZ_ML)      // 26112
#define SZ_WV    (69*KD)               // 4416
#define OFF_C    (OFF_WV + SZ_WV)      // 30528
#define OFF_PR   (OFF_C + 384)
#define OFF_LN   (OFF_PR + 384)
#define OFF_L    (OFF_LN + 384)        // 1152 floats
#define OFF_WB   (OFF_L + 1152)        // 2304 floats [m][dof][r]
#define OFF_DB   (OFF_WB + 2304)       // 768 floats  [dof][r]
#define OFF_BEQ  (OFF_DB + 768)        // 32
#define OFF_WACC (OFF_BEQ + 32)        // 80 (8 waves x 10)
#define OFF_ITA  (OFF_WACC + 80)       // 10
#define OFF_ACC  (OFF_ITA + 10)        // 2
#define LDS_FLOATS (OFF_ACC + 2)       // 36028 -> 144112 bytes

__device__ __forceinline__ float wave_sum64(float v) {
    #pragma unroll
    for (int off = 32; off > 0; off >>= 1) v += __shfl_xor(v, off, 64);
    return v;
}

// Build Qd = [[I + 2*rho*(Pd'Pd + Pdd'Pdd + P'P), E'],[E, 0]] (69x69) and invert it.
// Winv[j][k] = Qd^-1[j][k], j=0..68, k=0..63  (Qd symmetric -> rows of inverse suffice)
__global__ void precompute_winv(const float* __restrict__ P,
                                const float* __restrict__ Pd,
                                const float* __restrict__ Pdd,
                                float* __restrict__ Winv) {
    __shared__ float aug[69][140];   // cols 0..68 = Qd, cols 69..137 = identity -> inverse
    __shared__ float fac[69];
    __shared__ float invp;
    __shared__ int piv;
    const int t = threadIdx.x;  // 256 threads

    for (int idx = t; idx < 69*140; idx += 256) aug[idx/140][idx%140] = 0.f;
    __syncthreads();

    // top-left 64x64: I + 2*rho*(Pd'Pd + Pdd'Pdd + P'P)
    for (int idx = t; idx < 64*64; idx += 256) {
        int i = idx >> 6, j = idx & 63;
        float acc = 0.f;
        for (int r = 0; r < 128; ++r) {
            acc += Pd[r*64+i]*Pd[r*64+j];
            acc += Pdd[r*64+i]*Pdd[r*64+j];
            acc += P[r*64+i]*P[r*64+j];
        }
        aug[i][j] = (i == j ? 1.f : 0.f) + 2.f*RHO_F*acc;
    }
    // E rows: [P[0], Pd[0], Pdd[0], Pd[127], Pdd[127]]
    for (int idx = t; idx < 5*64; idx += 256) {
        int e = idx >> 6, k = idx & 63;
        float v = (e == 0) ? P[k] : (e == 1) ? Pd[k] : (e == 2) ? Pdd[k]
                : (e == 3) ? Pd[127*64+k] : Pdd[127*64+k];
        aug[k][64+e] = v;
        aug[64+e][k] = v;
    }
    for (int i = t; i < 69; i += 256) aug[i][69+i] = 1.f;
    __syncthreads();

    // Gauss-Jordan with partial pivoting
    for (int p = 0; p < 69; ++p) {
        if (t == 0) {
            int best = p; float bv = fabsf(aug[p][p]);
            for (int i = p+1; i < 69; ++i) {
                float a = fabsf(aug[i][p]);
                if (a > bv) { bv = a; best = i; }
            }
            piv = best;
        }
        __syncthreads();
        int pr = piv;
        if (pr != p) {
            for (int c = t; c < 138; c += 256) {
                float tmp = aug[p][c]; aug[p][c] = aug[pr][c]; aug[pr][c] = tmp;
            }
        }
        __syncthreads();
        if (t == 0) invp = 1.f / aug[p][p];
        __syncthreads();
        for (int c = t; c < 138; c += 256) aug[p][c] *= invp;
        __syncthreads();
        for (int i = t; i < 69; i += 256) fac[i] = aug[i][p];
        __syncthreads();
        for (int idx = t; idx < 69*138; idx += 256) {
            int i = idx / 138, c = idx % 138;
            if (i != p) aug[i][c] -= fac[i] * aug[p][c];
        }
        __syncthreads();
    }
    for (int idx = t; idx < 69*64; idx += 256) {
        int j = idx >> 6, k = idx & 63;
        Winv[idx] = aug[j][69+k];
    }
}

// Persistent ADMM: each block owns BPB batch elements, runs all 15 iterations in LDS.
// m0 = Pdot (bound 0.8), m1 = Pddot (1.8), m2 = P (pi).
__global__ void __launch_bounds__(TPB)
admm_kernel(const float* __restrict__ M0, const float* __restrict__ M1,
            const float* __restrict__ M2, const float* __restrict__ lamG,
            const float* __restrict__ cG, const float* __restrict__ beqG,
            const float* __restrict__ WinvG, float* __restrict__ outG) {
    extern __shared__ float s[];
    float* Ml   = s + OFF_ML;    // [m][r][MPAD], padded rows
    float* Wv   = s + OFF_WV;    // [69][64]
    float* cA   = s + OFF_C;     // [dof][64]
    float* prA  = s + OFF_PR;
    float* lnA  = s + OFF_LN;
    float* lA   = s + OFF_L;     // [m][dof][64]
    float* wB   = s + OFF_WB;    // [m][dof][128]
    float* dB   = s + OFF_DB;    // [dof][128]
    float* beqS = s + OFF_BEQ;   // 30 used
    float* wacc = s + OFF_WACC;  // [wave][10]: res0..2, sd0..2, ld0..2, cd
    float* itA  = s + OFF_ITA;
    float* accS = s + OFF_ACC;   // [0]=fp sum, [1]=rp sum

    const int t = threadIdx.x;
    const int lane = t & 63;
    const int wv = t >> 6;

    // ---- load matrices into LDS (padded), float4 ----
    for (int idx = t; idx < NMAT*NR*16; idx += TPB) {     // 6144 float4
        int m = idx >> 11;            // 2048 float4 per matrix
        int rem = idx & 2047;
        int r = rem >> 4, j = rem & 15;
        const float* src = (m == 0) ? M0 : ((m == 1) ? M1 : M2);
        float4 v = reinterpret_cast<const float4*>(src)[rem];
        reinterpret_cast<float4*>(&Ml[(m*NR + r)*MPAD])[j] = v;
    }
    for (int idx = t; idx < SZ_WV/4; idx += TPB)
        reinterpret_cast<float4*>(Wv)[idx] = reinterpret_cast<const float4*>(WinvG)[idx];
    __syncthreads();

    for (int bi = 0; bi < BPB; ++bi) {
        const int b = blockIdx.x * BPB + bi;

        for (int i = t; i < 96; i += TPB)
            reinterpret_cast<float4*>(cA)[i] = reinterpret_cast<const float4*>(cG + (size_t)b*384)[i];
        for (int i = t; i < 288; i += TPB)
            reinterpret_cast<float4*>(lA)[i] = reinterpret_cast<const float4*>(lamG + (size_t)b*1152)[i];
        if (t < 30) beqS[t] = beqG[b*30 + t];
        if (t == 0) { accS[0] = 0.f; accS[1] = 0.f; }
        __syncthreads();

        // ---- prologue: w = ax + clamp(ax,-b,b) from initial c ----
        for (int task = t; task < NMAT*NDF*NR; task += TPB) {
            int m = task / (NDF*NR);
            int rem = task % (NDF*NR);
            int dof = rem >> 7, r = rem & 127;
            const float4* Mr = reinterpret_cast<const float4*>(&Ml[(m*NR + r)*MPAD]);
            const float4* cv = reinterpret_cast<const float4*>(&cA[dof*KD]);
            float a0 = 0.f, a1 = 0.f, a2 = 0.f, a3 = 0.f;
            #pragma unroll
            for (int j = 0; j < 16; ++j) {
                float4 mv = Mr[j]; float4 pv = cv[j];
                a0 += mv.x*pv.x; a1 += mv.y*pv.y; a2 += mv.z*pv.z; a3 += mv.w*pv.w;
            }
            float ax = (a0+a1) + (a2+a3);
            float bm = (m == 0) ? 0.8f : ((m == 1) ? 1.8f : PI_F);
            float cl = fminf(bm, fmaxf(-bm, ax));
            wB[task] = ax + cl;
        }
        __syncthreads();

        for (int it = 0; it < NITER; ++it) {
            for (int i = t; i < 80; i += TPB) wacc[i] = 0.f;
            __syncthreads();

            // ---- STEP A: lincost ----
            if (t < 384) {
                int dof = t >> 6, k = t & 63;
                float acc = -(lA[(0*NDF+dof)*KD + k] + lA[(1*NDF+dof)*KD + k] + lA[(2*NDF+dof)*KD + k])
                            - RHO_F * cA[t];
                #pragma unroll
                for (int m = 0; m < 3; ++m) {
                    const float* Mcol = &Ml[(m*NR)*MPAD + k];
                    const float* wrow = &wB[m*768 + dof*128];
                    float s0 = 0.f, s1 = 0.f;
                    #pragma unroll 4
                    for (int r = 0; r < 128; r += 2) {
                        s0 += wrow[r]   * Mcol[r*MPAD];
                        s1 += wrow[r+1] * Mcol[(r+1)*MPAD];
                    }
                    acc -= RHO_F * (s0 + s1);
                }
                lnA[t] = acc;
            }
            __syncthreads();

            // ---- STEP B: primal + ||primal - c||^2 ----
            float cdsq = 0.f;
            if (t < 384) {
                int dof = t >> 6, k = t & 63;
                float acc = 0.f;
                const float* ln = &lnA[dof*KD];
                #pragma unroll 8
                for (int j = 0; j < 64; ++j) acc -= Wv[j*KD + k] * ln[j];
                const float* be = &beqS[dof*5];
                #pragma unroll
                for (int e = 0; e < 5; ++e) acc += Wv[(64+e)*KD + k] * be[e];
                prA[t] = acc;
                float cd = acc - cA[t];
                cdsq = cd * cd;
            }
            cdsq = wave_sum64(cdsq);
            if (lane == 0) wacc[wv*10 + 9] = cdsq;
            __syncthreads();

            // ---- STEP C per matrix ----
            #pragma unroll 1
            for (int m = 0; m < 3; ++m) {
                const float bm = (m == 0) ? 0.8f : ((m == 1) ? 1.8f : PI_F);
                float resq = 0.f, sdq = 0.f;
                for (int task = t; task < NDF*NR; task += TPB) {
                    int dof = task >> 7, r = task & 127;
                    const float4* Mr = reinterpret_cast<const float4*>(&Ml[(m*NR + r)*MPAD]);
                    const float4* pv4 = reinterpret_cast<const float4*>(&prA[dof*KD]);
                    float a0 = 0.f, a1 = 0.f, a2 = 0.f, a3 = 0.f;
                    #pragma unroll
                    for (int j = 0; j < 16; ++j) {
                        float4 mv = Mr[j]; float4 pv = pv4[j];
                        a0 += mv.x*pv.x; a1 += mv.y*pv.y; a2 += mv.z*pv.z; a3 += mv.w*pv.w;
                    }
                    float axn = (a0+a1) + (a2+a3);
                    float wo = wB[m*768 + task];
                    float axo = wo - fminf(bm, fmaxf(-bm, 0.5f*wo));  // invert w(ax)
                    float cln = fminf(bm, fmaxf(-bm, axn));
                    float d = axn - cln;                               // res_plus - res_minus
                    resq += d*d;
                    float snp = fmaxf(0.f, bm - axn), snm = fmaxf(0.f, bm + axn);
                    float sop = fmaxf(0.f, bm - axo), som = fmaxf(0.f, bm + axo);
                    float d1 = snp - sop, d2 = snm - som;
                    sdq += d1*d1 + d2*d2;
                    dB[task] = d;
                    wB[m*768 + task] = axn + cln;                      // w for next iter
                }
                resq = wave_sum64(resq);
                sdq = wave_sum64(sdq);
                if (lane == 0) { wacc[wv*10 + m] = resq; wacc[wv*10 + 3 + m] = sdq; }
                __syncthreads();

                // lam update: g[k] = sum_r d[r]*M[r,k]
                float ldq = 0.f;
                if (t < 384) {
                    int dof = t >> 6, k = t & 63;
                    const float* Mcol = &Ml[(m*NR)*MPAD + k];
                    const float* dr = &dB[dof*128];
                    float s0 = 0.f, s1 = 0.f;
                    #pragma unroll 4
                    for (int r = 0; r < 128; r += 2) {
                        s0 += dr[r]   * Mcol[r*MPAD];
                        s1 += dr[r+1] * Mcol[(r+1)*MPAD];
                    }
                    float delta = RHO_F * (s0 + s1);
                    int li = (m*NDF + dof)*KD + k;
                    lA[li] -= delta;
                    ldq = delta * delta;
                }
                ldq = wave_sum64(ldq);
                if (lane == 0) wacc[wv*10 + 6 + m] = ldq;
                __syncthreads();
            }

            // ---- STEP D: combine norms, c <- primal ----
            if (t < 384) cA[t] = prA[t];
            if (t < 10) {
                float v = 0.f;
                #pragma unroll
                for (int w = 0; w < 8; ++w) v += wacc[w*10 + t];
                itA[t] = v;
            }
            __syncthreads();
            if (t == 0) {
                float rp = sqrtf(itA[0]) + sqrtf(itA[1]) + sqrtf(itA[2]);
                float fp = sqrtf(itA[3]) + sqrtf(itA[4]) + sqrtf(itA[5])
                         + sqrtf(itA[6]) + sqrtf(itA[7]) + sqrtf(itA[8]) + sqrtf(itA[9]);
                accS[1] += rp;
                accS[0] += fp;
            }
            __syncthreads();
        }

        // ---- write outputs ----
        for (int i = t; i < 96; i += TPB)
            reinterpret_cast<float4*>(outG + (size_t)b*384)[i] = reinterpret_cast<float4*>(cA)[i];
        if (t == 0) {
            outG[(size_t)NBATCH*384 + b]          = accS[0] / 15.f;   // acc_res_fixed
            outG[(size_t)NBATCH*384 + NBATCH + b] = accS[1] / 15.f;   // acc_res_primal
        }
        __syncthreads();
    }
}

extern "C" void kernel_launch(void* const* d_in, const int* in_sizes, int n_in,
                              void* d_out, int out_size, void* d_ws, size_t ws_size,
                              hipStream_t stream) {
    const float* P     = (const float*)d_in[0];
    const float* Pdot  = (const float*)d_in[1];
    const float* Pddot = (const float*)d_in[2];
    const float* lam   = (const float*)d_in[3];
    const float* csamp = (const float*)d_in[4];
    const float* beq   = (const float*)d_in[5];
    float* Winv = (float*)d_ws;           // 69*64 floats
    float* out  = (float*)d_out;

    hipLaunchKernelGGL(precompute_winv, dim3(1), dim3(256), 0, stream, P, Pdot, Pddot, Winv);

    const int ldsBytes = LDS_FLOATS * 4;  // 144112
    hipFuncSetAttribute((const void*)admm_kernel,
                        hipFuncAttributeMaxDynamicSharedMemorySize, ldsBytes);
    hipLaunchKernelGGL(admm_kernel, dim3(NBATCH/BPB), dim3(TPB), ldsBytes, stream,
                       Pdot, Pddot, P, lam, csamp, beq, Winv, out);
}

// Round 2
// 901.940 us; speedup vs baseline: 5.1728x; 5.1728x over previous
//
#include <hip/hip_runtime.h>
#include <math.h>

#define NITER 15
#define TPB 512
#define NBATCH 4096
#define NBPB 16
#define PI_F 3.14159265358979323846f

typedef __attribute__((ext_vector_type(8))) short short8;
typedef __attribute__((ext_vector_type(4))) float f32x4;
typedef __attribute__((ext_vector_type(4))) unsigned short ushort4v;

// ---------------- LDS layout (bytes) ----------------
// region1: dBuf [pl2][dof6][b16][136 bf16] = 52224   (aliases lnBuf [pl2][dof6][b16][72] = 27648)
// region2: prBuf [pl2][dof6][b16][72 bf16] = 27648
// region3: wBuf  (like dBuf) = 52224
// wacc[10][16] f32 = 640 ; accN[2][16] f32 = 128
#define LDS_D0   0
#define LDS_LN   0
#define LDS_PR   52224
#define LDS_W0   79872
#define LDS_WACC 132096
#define LDS_ACCN 132736
#define LDS_TOTAL 132864

// ---------------- ws layout ----------------
// WinvG f32 [69][64] @ 0 (17664 B), frags @ 17920:
//   MA  ushort [3][8][2][2][64][8]  = 49152 elems
//   MTA ushort [3][4][4][2][64][8]  = 49152
//   WVA ushort [4][2][2][64][8]     = 8192
#define WS_FRAG_OFF 17920

__device__ __forceinline__ unsigned short bf16_rne(float x) {
    unsigned u = __float_as_uint(x);
    unsigned r = (u + 0x7FFFu + ((u >> 16) & 1u)) >> 16;
    return (unsigned short)r;
}
__device__ __forceinline__ float bf16_f32(unsigned short h) {
    return __uint_as_float(((unsigned)h) << 16);
}

// ===================== K1: invert Qd (69x69) =====================
__global__ void precompute_winv(const float* __restrict__ P,
                                const float* __restrict__ Pd,
                                const float* __restrict__ Pdd,
                                float* __restrict__ Winv) {
    __shared__ float aug[69][140];
    __shared__ float fac[69];
    __shared__ float invp;
    __shared__ int piv;
    const int t = threadIdx.x;  // 256

    for (int idx = t; idx < 69*140; idx += 256) aug[idx/140][idx%140] = 0.f;
    __syncthreads();
    for (int idx = t; idx < 64*64; idx += 256) {
        int i = idx >> 6, j = idx & 63;
        float acc = 0.f;
        for (int r = 0; r < 128; ++r) {
            acc += Pd[r*64+i]*Pd[r*64+j];
            acc += Pdd[r*64+i]*Pdd[r*64+j];
            acc += P[r*64+i]*P[r*64+j];
        }
        aug[i][j] = (i == j ? 1.f : 0.f) + 2.f*acc;
    }
    for (int idx = t; idx < 5*64; idx += 256) {
        int e = idx >> 6, k = idx & 63;
        float v = (e == 0) ? P[k] : (e == 1) ? Pd[k] : (e == 2) ? Pdd[k]
                : (e == 3) ? Pd[127*64+k] : Pdd[127*64+k];
        aug[k][64+e] = v;
        aug[64+e][k] = v;
    }
    for (int i = t; i < 69; i += 256) aug[i][69+i] = 1.f;
    __syncthreads();
    for (int p = 0; p < 69; ++p) {
        if (t == 0) {
            int best = p; float bv = fabsf(aug[p][p]);
            for (int i = p+1; i < 69; ++i) { float a = fabsf(aug[i][p]); if (a > bv) { bv = a; best = i; } }
            piv = best;
        }
        __syncthreads();
        int pr = piv;
        if (pr != p) for (int c = t; c < 138; c += 256) { float tmp = aug[p][c]; aug[p][c] = aug[pr][c]; aug[pr][c] = tmp; }
        __syncthreads();
        if (t == 0) invp = 1.f / aug[p][p];
        __syncthreads();
        for (int c = t; c < 138; c += 256) aug[p][c] *= invp;
        __syncthreads();
        for (int i = t; i < 69; i += 256) fac[i] = aug[i][p];
        __syncthreads();
        for (int idx = t; idx < 69*138; idx += 256) {
            int i = idx / 138, c = idx % 138;
            if (i != p) aug[i][c] -= fac[i] * aug[p][c];
        }
        __syncthreads();
    }
    for (int idx = t; idx < 69*64; idx += 256) Winv[idx] = aug[idx>>6][69 + (idx & 63)];
}

// ===================== K2: pack bf16 hi/lo MFMA A-fragments =====================
// A-frag mapping (16x16x32): row = lane&15, k = (lane>>4)*8 + j
__global__ void pack_frags(const float* __restrict__ P, const float* __restrict__ Pd,
                           const float* __restrict__ Pdd, const float* __restrict__ WinvG,
                           unsigned short* __restrict__ MA, unsigned short* __restrict__ MTA,
                           unsigned short* __restrict__ WVA) {
    int tid = blockIdx.x*256 + threadIdx.x;
    if (tid < 49152) {                       // MA [m][rt8][ks2][pl2][lane][8] ; A = M[r][k]
        int j = tid & 7, lane = (tid>>3)&63, pl = (tid>>9)&1, ks = (tid>>10)&1, rt = (tid>>11)&7, m = tid>>14;
        const float* src = (m==0) ? Pd : ((m==1) ? Pdd : P);
        int r = rt*16 + (lane&15);
        int k = ks*32 + (lane>>4)*8 + j;
        float x = src[r*64+k];
        unsigned short hi = bf16_rne(x);
        MA[tid] = pl ? bf16_rne(x - bf16_f32(hi)) : hi;
    } else if (tid < 98304) {                // MTA [m][kt4][ks4][pl2][lane][8] ; A = M^T[k][r]
        int t2 = tid - 49152;
        int j = t2 & 7, lane = (t2>>3)&63, pl = (t2>>9)&1, ks = (t2>>10)&3, kt = (t2>>12)&3, m = t2>>14;
        const float* src = (m==0) ? Pd : ((m==1) ? Pdd : P);
        int k = kt*16 + (lane&15);
        int r = ks*32 + (lane>>4)*8 + j;
        float x = src[r*64+k];
        unsigned short hi = bf16_rne(x);
        MTA[t2] = pl ? bf16_rne(x - bf16_f32(hi)) : hi;
    } else if (tid < 106496) {               // WVA [kt4][js2][pl2][lane][8] ; A = Winv[k'][jj] = WinvG[jj][k']
        int t3 = tid - 98304;
        int j = t3 & 7, lane = (t3>>3)&63, pl = (t3>>9)&1, js = (t3>>10)&1, kt = t3>>11;
        int kp = kt*16 + (lane&15);
        int jj = js*32 + (lane>>4)*8 + j;
        float x = WinvG[jj*64 + kp];
        unsigned short hi = bf16_rne(x);
        WVA[t3] = pl ? bf16_rne(x - bf16_f32(hi)) : hi;
    }
}

// ===================== main ADMM kernel =====================
__device__ __forceinline__ f32x4 mfma16(short8 a, short8 b, f32x4 c) {
    return __builtin_amdgcn_mfma_f32_16x16x32_bf16(a, b, c, 0, 0, 0);
}

__global__ void __launch_bounds__(TPB, 2)
admm_kernel(const float* __restrict__ lamG, const float* __restrict__ cG,
            const float* __restrict__ beqG, const float* __restrict__ WinvG,
            const unsigned short* __restrict__ MA, const unsigned short* __restrict__ MTA,
            const unsigned short* __restrict__ WVA, float* __restrict__ outG) {
    extern __shared__ char sm[];
    float* waccF = (float*)(sm + LDS_WACC);   // [10][16]
    float* accN  = (float*)(sm + LDS_ACCN);   // [2][16]: 0..15 fp, 16..31 rp

    const int t = threadIdx.x;
    const int lane = t & 63;
    const int w = t >> 6;
    const int b = lane & 15;
    const int q = lane >> 4;
    const int kt = w & 3;          // (dof,kt)-phase: wave's ktile
    const int dhi = w >> 2;        // dof = du*2 + dhi
    const int rt = w;              // C-phase rtile
    const int bbase = blockIdx.x * NBPB;

    // persistent register state (all statically indexed)
    float lR[3][3][4];   // [m][du][reg]
    float uR[3][3][4];
    float cR[3][4];
    float pbq[3][4];
    unsigned axp[3][6][2];  // packed bf16 pairs of previous ax, [m][dof][pair]

    // ---- init LDS accum ----
    for (int i = t; i < 160 + 32; i += TPB) ((float*)(sm + LDS_WACC))[i] = 0.f;

    // ---- load c, l, compute beq-projection ----
    #pragma unroll
    for (int du = 0; du < 3; ++du) {
        int dof = du*2 + dhi;
        #pragma unroll
        for (int reg = 0; reg < 4; ++reg) {
            int k = kt*16 + q*4 + reg;
            cR[du][reg] = cG[(size_t)(bbase+b)*384 + dof*64 + k];
            #pragma unroll
            for (int m = 0; m < 3; ++m)
                lR[m][du][reg] = lamG[(size_t)(bbase+b)*1152 + m*384 + dof*64 + k];
            float s = 0.f;
            #pragma unroll
            for (int e = 0; e < 5; ++e)
                s += WinvG[(64+e)*64 + k] * beqG[(size_t)(bbase+b)*30 + dof*5 + e];
            pbq[du][reg] = s;
        }
    }

    // ---- write c split into prBuf ----
    #pragma unroll
    for (int du = 0; du < 3; ++du) {
        int dof = du*2 + dhi;
        ushort4v hi4, lo4;
        #pragma unroll
        for (int reg = 0; reg < 4; ++reg) {
            unsigned short h = bf16_rne(cR[du][reg]);
            hi4[reg] = h;
            lo4[reg] = bf16_rne(cR[du][reg] - bf16_f32(h));
        }
        int off = (kt*16 + q*4)*2;
        *(ushort4v*)(sm + LDS_PR + ((0*6+dof)*16 + b)*144 + off) = hi4;
        *(ushort4v*)(sm + LDS_PR + ((1*6+dof)*16 + b)*144 + off) = lo4;
    }
    __syncthreads();

    // ---- prologue: per m, ax0 = M c -> w0 -> u0 = l0 + w0@A ----
    for (int m = 0; m < 3; ++m) {
        const float bm = (m==0) ? 0.8f : ((m==1) ? 1.8f : PI_F);
        // C-like: compute ax0, write w0 split, init axp
        short8 aMh[2], aMl[2];
        #pragma unroll
        for (int ks = 0; ks < 2; ++ks) {
            aMh[ks] = *(const short8*)(MA + ((((m*8+rt)*2+ks)*2+0)*512 + lane*8));
            aMl[ks] = *(const short8*)(MA + ((((m*8+rt)*2+ks)*2+1)*512 + lane*8));
        }
        #pragma unroll
        for (int dof = 0; dof < 6; ++dof) {
            f32x4 acc = {0.f,0.f,0.f,0.f};
            #pragma unroll
            for (int ks = 0; ks < 2; ++ks) {
                short8 Bh = *(const short8*)(sm + LDS_PR + ((0*6+dof)*16 + b)*144 + (ks*32 + q*8)*2);
                short8 Bl = *(const short8*)(sm + LDS_PR + ((1*6+dof)*16 + b)*144 + (ks*32 + q*8)*2);
                acc = mfma16(aMh[ks], Bh, acc);
                acc = mfma16(aMh[ks], Bl, acc);
                acc = mfma16(aMl[ks], Bh, acc);
            }
            ushort4v wh, wl;
            unsigned short axh[4];
            #pragma unroll
            for (int reg = 0; reg < 4; ++reg) {
                float axn = acc[reg];
                float cl = fminf(bm, fmaxf(-bm, axn));
                float wv = axn + cl;
                unsigned short h = bf16_rne(wv);
                wh[reg] = h;
                wl[reg] = bf16_rne(wv - bf16_f32(h));
                axh[reg] = bf16_rne(axn);
            }
            int off = (rt*16 + q*4)*2;
            *(ushort4v*)(sm + LDS_W0 + ((0*6+dof)*16 + b)*272 + off) = wh;
            *(ushort4v*)(sm + LDS_W0 + ((1*6+dof)*16 + b)*272 + off) = wl;
            axp[m][dof][0] = ((unsigned)axh[1] << 16) | axh[0];
            axp[m][dof][1] = ((unsigned)axh[3] << 16) | axh[2];
        }
        __syncthreads();
        // D-like: u0 = l0 + w0@A  (h-chain only)
        short8 aTh[4], aTl[4];
        #pragma unroll
        for (int ks = 0; ks < 4; ++ks) {
            aTh[ks] = *(const short8*)(MTA + (((((m*4+kt)*4+ks)*2+0)*512) + lane*8));
            aTl[ks] = *(const short8*)(MTA + (((((m*4+kt)*4+ks)*2+1)*512) + lane*8));
        }
        #pragma unroll
        for (int du = 0; du < 3; ++du) {
            int dof = du*2 + dhi;
            f32x4 accH = {0.f,0.f,0.f,0.f};
            #pragma unroll
            for (int ks = 0; ks < 4; ++ks) {
                short8 Bwh = *(const short8*)(sm + LDS_W0 + ((0*6+dof)*16 + b)*272 + (ks*32 + q*8)*2);
                short8 Bwl = *(const short8*)(sm + LDS_W0 + ((1*6+dof)*16 + b)*272 + (ks*32 + q*8)*2);
                accH = mfma16(aTh[ks], Bwh, accH);
                accH = mfma16(aTh[ks], Bwl, accH);
                accH = mfma16(aTl[ks], Bwh, accH);
            }
            #pragma unroll
            for (int reg = 0; reg < 4; ++reg)
                uR[m][du][reg] = lR[m][du][reg] + accH[reg];
        }
        __syncthreads();
    }

    // ==================== 15 iterations ====================
    for (int it = 0; it < NITER; ++it) {
        // ---- phase A: t = sum_m u + c -> split -> lnBuf ----
        #pragma unroll
        for (int du = 0; du < 3; ++du) {
            int dof = du*2 + dhi;
            ushort4v hi4, lo4;
            #pragma unroll
            for (int reg = 0; reg < 4; ++reg) {
                float tv = uR[0][du][reg] + uR[1][du][reg] + uR[2][du][reg] + cR[du][reg];
                unsigned short h = bf16_rne(tv);
                hi4[reg] = h;
                lo4[reg] = bf16_rne(tv - bf16_f32(h));
            }
            int off = (kt*16 + q*4)*2;
            *(ushort4v*)(sm + LDS_LN + ((0*6+dof)*16 + b)*144 + off) = hi4;
            *(ushort4v*)(sm + LDS_LN + ((1*6+dof)*16 + b)*144 + off) = lo4;
        }
        __syncthreads();

        // ---- phase B: pr = Winv * t + pbq ----
        {
            short8 aWh[2], aWl[2];
            #pragma unroll
            for (int js = 0; js < 2; ++js) {
                aWh[js] = *(const short8*)(WVA + (((kt*2+js)*2+0)*512 + lane*8));
                aWl[js] = *(const short8*)(WVA + (((kt*2+js)*2+1)*512 + lane*8));
            }
            float cdq = 0.f;
            #pragma unroll
            for (int du = 0; du < 3; ++du) {
                int dof = du*2 + dhi;
                f32x4 acc = {0.f,0.f,0.f,0.f};
                #pragma unroll
                for (int js = 0; js < 2; ++js) {
                    short8 Bh = *(const short8*)(sm + LDS_LN + ((0*6+dof)*16 + b)*144 + (js*32 + q*8)*2);
                    short8 Bl = *(const short8*)(sm + LDS_LN + ((1*6+dof)*16 + b)*144 + (js*32 + q*8)*2);
                    acc = mfma16(aWh[js], Bh, acc);
                    acc = mfma16(aWh[js], Bl, acc);
                    acc = mfma16(aWl[js], Bh, acc);
                }
                ushort4v hi4, lo4;
                #pragma unroll
                for (int reg = 0; reg < 4; ++reg) {
                    float pr = acc[reg] + pbq[du][reg];
                    float cd = pr - cR[du][reg];
                    cdq += cd * cd;
                    cR[du][reg] = pr;
                    unsigned short h = bf16_rne(pr);
                    hi4[reg] = h;
                    lo4[reg] = bf16_rne(pr - bf16_f32(h));
                }
                int off = (kt*16 + q*4)*2;
                *(ushort4v*)(sm + LDS_PR + ((0*6+dof)*16 + b)*144 + off) = hi4;
                *(ushort4v*)(sm + LDS_PR + ((1*6+dof)*16 + b)*144 + off) = lo4;
            }
            cdq += __shfl_xor(cdq, 16, 64);
            cdq += __shfl_xor(cdq, 32, 64);
            if (lane < 16) atomicAdd(&waccF[9*16 + b], cdq);
        }
        __syncthreads();

        // ---- phases C/D per m ----
        for (int m = 0; m < 3; ++m) {
            const float bm = (m==0) ? 0.8f : ((m==1) ? 1.8f : PI_F);
            // C: ax = M*pr ; d, w', norms, ax_old
            short8 aMh[2], aMl[2];
            #pragma unroll
            for (int ks = 0; ks < 2; ++ks) {
                aMh[ks] = *(const short8*)(MA + ((((m*8+rt)*2+ks)*2+0)*512 + lane*8));
                aMl[ks] = *(const short8*)(MA + ((((m*8+rt)*2+ks)*2+1)*512 + lane*8));
            }
            float resq = 0.f, sdq = 0.f;
            #pragma unroll
            for (int dof = 0; dof < 6; ++dof) {
                f32x4 acc = {0.f,0.f,0.f,0.f};
                #pragma unroll
                for (int ks = 0; ks < 2; ++ks) {
                    short8 Bh = *(const short8*)(sm + LDS_PR + ((0*6+dof)*16 + b)*144 + (ks*32 + q*8)*2);
                    short8 Bl = *(const short8*)(sm + LDS_PR + ((1*6+dof)*16 + b)*144 + (ks*32 + q*8)*2);
                    acc = mfma16(aMh[ks], Bh, acc);
                    acc = mfma16(aMh[ks], Bl, acc);
                    acc = mfma16(aMl[ks], Bh, acc);
                }
                ushort4v dh, dl, wh, wl;
                unsigned short axh[4];
                unsigned p0 = axp[m][dof][0], p1 = axp[m][dof][1];
                #pragma unroll
                for (int reg = 0; reg < 4; ++reg) {
                    float axn = acc[reg];
                    float axo = bf16_f32((unsigned short)((reg < 2 ? p0 >> (16*reg) : p1 >> (16*(reg-2))) & 0xFFFF));
                    float cl = fminf(bm, fmaxf(-bm, axn));
                    float d  = axn - cl;
                    float wv = axn + cl;
                    resq += d * d;
                    float d1 = fmaxf(0.f, bm - axn) - fmaxf(0.f, bm - axo);
                    float d2 = fmaxf(0.f, bm + axn) - fmaxf(0.f, bm + axo);
                    sdq += d1*d1 + d2*d2;
                    unsigned short h = bf16_rne(d);
                    dh[reg] = h; dl[reg] = bf16_rne(d - bf16_f32(h));
                    h = bf16_rne(wv);
                    wh[reg] = h; wl[reg] = bf16_rne(wv - bf16_f32(h));
                    axh[reg] = bf16_rne(axn);
                }
                int off = (rt*16 + q*4)*2;
                *(ushort4v*)(sm + LDS_D0 + ((0*6+dof)*16 + b)*272 + off) = dh;
                *(ushort4v*)(sm + LDS_D0 + ((1*6+dof)*16 + b)*272 + off) = dl;
                *(ushort4v*)(sm + LDS_W0 + ((0*6+dof)*16 + b)*272 + off) = wh;
                *(ushort4v*)(sm + LDS_W0 + ((1*6+dof)*16 + b)*272 + off) = wl;
                axp[m][dof][0] = ((unsigned)axh[1] << 16) | axh[0];
                axp[m][dof][1] = ((unsigned)axh[3] << 16) | axh[2];
            }
            resq += __shfl_xor(resq, 16, 64); resq += __shfl_xor(resq, 32, 64);
            sdq  += __shfl_xor(sdq, 16, 64);  sdq  += __shfl_xor(sdq, 32, 64);
            if (lane < 16) {
                atomicAdd(&waccF[m*16 + b], resq);
                atomicAdd(&waccF[(3+m)*16 + b], sdq);
            }
            __syncthreads();

            // D: delta = M^T d ; h = M^T w' ; l -= delta ; u = l + h
            short8 aTh[4], aTl[4];
            #pragma unroll
            for (int ks = 0; ks < 4; ++ks) {
                aTh[ks] = *(const short8*)(MTA + (((((m*4+kt)*4+ks)*2+0)*512) + lane*8));
                aTl[ks] = *(const short8*)(MTA + (((((m*4+kt)*4+ks)*2+1)*512) + lane*8));
            }
            float ldq = 0.f;
            #pragma unroll
            for (int du = 0; du < 3; ++du) {
                int dof = du*2 + dhi;
                f32x4 accD = {0.f,0.f,0.f,0.f};
                f32x4 accH = {0.f,0.f,0.f,0.f};
                #pragma unroll
                for (int ks = 0; ks < 4; ++ks) {
                    short8 Bdh = *(const short8*)(sm + LDS_D0 + ((0*6+dof)*16 + b)*272 + (ks*32 + q*8)*2);
                    short8 Bdl = *(const short8*)(sm + LDS_D0 + ((1*6+dof)*16 + b)*272 + (ks*32 + q*8)*2);
                    short8 Bwh = *(const short8*)(sm + LDS_W0 + ((0*6+dof)*16 + b)*272 + (ks*32 + q*8)*2);
                    short8 Bwl = *(const short8*)(sm + LDS_W0 + ((1*6+dof)*16 + b)*272 + (ks*32 + q*8)*2);
                    accD = mfma16(aTh[ks], Bdh, accD);
                    accD = mfma16(aTh[ks], Bdl, accD);
                    accD = mfma16(aTl[ks], Bdh, accD);
                    accH = mfma16(aTh[ks], Bwh, accH);
                    accH = mfma16(aTh[ks], Bwl, accH);
                    accH = mfma16(aTl[ks], Bwh, accH);
                }
                #pragma unroll
                for (int reg = 0; reg < 4; ++reg) {
                    float delta = accD[reg];
                    float ln2 = lR[m][du][reg] - delta;
                    lR[m][du][reg] = ln2;
                    ldq += delta * delta;
                    uR[m][du][reg] = ln2 + accH[reg];
                }
            }
            ldq += __shfl_xor(ldq, 16, 64); ldq += __shfl_xor(ldq, 32, 64);
            if (lane < 16) atomicAdd(&waccF[(6+m)*16 + b], ldq);
            __syncthreads();
        }

        // ---- fold norms ----
        if (t < 16) {
            float rp = sqrtf(waccF[0*16+t]) + sqrtf(waccF[1*16+t]) + sqrtf(waccF[2*16+t]);
            float fp = sqrtf(waccF[3*16+t]) + sqrtf(waccF[4*16+t]) + sqrtf(waccF[5*16+t])
                     + sqrtf(waccF[6*16+t]) + sqrtf(waccF[7*16+t]) + sqrtf(waccF[8*16+t])
                     + sqrtf(waccF[9*16+t]);
            accN[t]      += fp;
            accN[16 + t] += rp;
            #pragma unroll
            for (int n = 0; n < 10; ++n) waccF[n*16+t] = 0.f;
        }
        __syncthreads();
    }

    // ---- outputs ----
    #pragma unroll
    for (int du = 0; du < 3; ++du) {
        int dof = du*2 + dhi;
        #pragma unroll
        for (int reg = 0; reg < 4; ++reg) {
            int k = kt*16 + q*4 + reg;
            outG[(size_t)(bbase+b)*384 + dof*64 + k] = cR[du][reg];
        }
    }
    if (t < 16) {
        outG[(size_t)NBATCH*384 + bbase + t]          = accN[t] / 15.f;
        outG[(size_t)NBATCH*384 + NBATCH + bbase + t] = accN[16 + t] / 15.f;
    }
}

extern "C" void kernel_launch(void* const* d_in, const int* in_sizes, int n_in,
                              void* d_out, int out_size, void* d_ws, size_t ws_size,
                              hipStream_t stream) {
    const float* P     = (const float*)d_in[0];
    const float* Pdot  = (const float*)d_in[1];
    const float* Pddot = (const float*)d_in[2];
    const float* lam   = (const float*)d_in[3];
    const float* csamp = (const float*)d_in[4];
    const float* beq   = (const float*)d_in[5];
    float* out = (float*)d_out;

    float* WinvG = (float*)d_ws;
    unsigned short* MA  = (unsigned short*)((char*)d_ws + WS_FRAG_OFF);
    unsigned short* MTA = MA + 49152;
    unsigned short* WVA = MTA + 49152;

    hipLaunchKernelGGL(precompute_winv, dim3(1), dim3(256), 0, stream, P, Pdot, Pddot, WinvG);
    hipLaunchKernelGGL(pack_frags, dim3(416), dim3(256), 0, stream, P, Pdot, Pddot, WinvG, MA, MTA, WVA);

    hipFuncSetAttribute((const void*)admm_kernel,
                        hipFuncAttributeMaxDynamicSharedMemorySize, LDS_TOTAL);
    hipLaunchKernelGGL(admm_kernel, dim3(NBATCH/NBPB), dim3(TPB), LDS_TOTAL, stream,
                       lam, csamp, beq, WinvG, MA, MTA, WVA, out);
}

// Round 9
// 805.932 us; speedup vs baseline: 5.7890x; 1.1191x over previous
//
#include <hip/hip_runtime.h>
#include <math.h>

#define NITER 15
#define TPB 512
#define NBATCH 4096
#define NBPB 16
#define PI_F 3.14159265358979323846f

typedef __attribute__((ext_vector_type(8))) short short8;
typedef __attribute__((ext_vector_type(4))) float f32x4;
typedef __attribute__((ext_vector_type(4))) unsigned short ushort4v;

// ---------------- LDS layout (bytes) ----------------
#define LDS_D0   0
#define LDS_LN   0
#define LDS_PR   52224
#define LDS_W0   79872
#define LDS_WACC 132096
#define LDS_ACCN 132736
#define LDS_TOTAL 132864

// ---------------- ws layout ----------------
// [0, 17664): QdG (4416 floats) -> overwritten by Winv[69][64]
#define WS_FRAG_OFF 17920

__device__ __forceinline__ unsigned short bf16_rne(float x) {
    unsigned u = __float_as_uint(x);
    unsigned r = (u + 0x7FFFu + ((u >> 16) & 1u)) >> 16;
    return (unsigned short)r;
}
__device__ __forceinline__ float bf16_f32(unsigned short h) {
    return __uint_as_float(((unsigned)h) << 16);
}

// ===================== K0: build Qd entries (fully parallel) =====================
__global__ void build_qd(const float* __restrict__ P, const float* __restrict__ Pd,
                         const float* __restrict__ Pdd, float* __restrict__ QdG) {
    int idx = blockIdx.x*256 + threadIdx.x;
    if (idx < 4096) {
        int i = idx >> 6, j = idx & 63;
        float acc = 0.f;
        for (int r = 0; r < 128; ++r) {
            acc += Pd[r*64+i]*Pd[r*64+j];
            acc += Pdd[r*64+i]*Pdd[r*64+j];
            acc += P[r*64+i]*P[r*64+j];
        }
        QdG[idx] = (i == j ? 1.f : 0.f) + 2.f*acc;
    } else if (idx < 4416) {
        int r2 = idx - 4096;
        int e = r2 >> 6, k = r2 & 63;
        float v = (e == 0) ? P[k] : (e == 1) ? Pd[k] : (e == 2) ? Pdd[k]
                : (e == 3) ? Pd[127*64+k] : Pdd[127*64+k];
        QdG[idx] = v;
    }
}

// ===================== K1: invert Qd — R2-verbatim GJ, STATIC shared ===========
__global__ void invert_qd(const float* __restrict__ QdG, float* __restrict__ Winv) {
    __shared__ float aug[69][140];
    __shared__ float fac[69];
    __shared__ float invp;
    __shared__ int piv;
    const int t = threadIdx.x;  // 256

    for (int idx = t; idx < 69*140; idx += 256) aug[idx/140][idx%140] = 0.f;
    __syncthreads();
    for (int idx = t; idx < 4096; idx += 256) aug[idx >> 6][idx & 63] = QdG[idx];
    for (int idx = t; idx < 320; idx += 256) {
        int e = idx >> 6, k = idx & 63;
        float v = QdG[4096 + idx];
        aug[k][64+e] = v;
        aug[64+e][k] = v;
    }
    for (int i = t; i < 69; i += 256) aug[i][69+i] = 1.f;
    __syncthreads();

    for (int p = 0; p < 69; ++p) {
        if (t == 0) {
            int best = p; float bv = fabsf(aug[p][p]);
            for (int i = p+1; i < 69; ++i) { float a = fabsf(aug[i][p]); if (a > bv) { bv = a; best = i; } }
            piv = best;
        }
        __syncthreads();
        int pr = piv;
        if (pr != p) for (int c = t; c < 138; c += 256) { float tmp = aug[p][c]; aug[p][c] = aug[pr][c]; aug[pr][c] = tmp; }
        __syncthreads();
        if (t == 0) invp = 1.f / aug[p][p];
        __syncthreads();
        for (int c = t; c < 138; c += 256) aug[p][c] *= invp;
        __syncthreads();
        for (int i = t; i < 69; i += 256) fac[i] = aug[i][p];
        __syncthreads();
        for (int idx = t; idx < 69*138; idx += 256) {
            int i = idx / 138, c = idx % 138;
            if (i != p) aug[i][c] -= fac[i] * aug[p][c];
        }
        __syncthreads();
    }
    for (int idx = t; idx < 69*64; idx += 256) Winv[idx] = aug[idx >> 6][69 + (idx & 63)];
}

// ===================== K2: pack bf16 hi/lo MFMA A-fragments =====================
__global__ void pack_frags(const float* __restrict__ P, const float* __restrict__ Pd,
                           const float* __restrict__ Pdd, const float* __restrict__ WinvG,
                           unsigned short* __restrict__ MA, unsigned short* __restrict__ MTA,
                           unsigned short* __restrict__ WVA) {
    int tid = blockIdx.x*256 + threadIdx.x;
    if (tid < 49152) {                       // MA [m][rt8][ks2][pl2][lane][8] ; A = M[r][k]
        int j = tid & 7, lane = (tid>>3)&63, pl = (tid>>9)&1, ks = (tid>>10)&1, rt = (tid>>11)&7, m = tid>>14;
        const float* src = (m==0) ? Pd : ((m==1) ? Pdd : P);
        int r = rt*16 + (lane&15);
        int k = ks*32 + (lane>>4)*8 + j;
        float x = src[r*64+k];
        unsigned short hi = bf16_rne(x);
        MA[tid] = pl ? bf16_rne(x - bf16_f32(hi)) : hi;
    } else if (tid < 98304) {                // MTA [m][kt4][ks4][pl2][lane][8] ; A = M^T[k][r]
        int t2 = tid - 49152;
        int j = t2 & 7, lane = (t2>>3)&63, pl = (t2>>9)&1, ks = (t2>>10)&3, kt = (t2>>12)&3, m = t2>>14;
        const float* src = (m==0) ? Pd : ((m==1) ? Pdd : P);
        int k = kt*16 + (lane&15);
        int r = ks*32 + (lane>>4)*8 + j;
        float x = src[r*64+k];
        unsigned short hi = bf16_rne(x);
        MTA[t2] = pl ? bf16_rne(x - bf16_f32(hi)) : hi;
    } else if (tid < 106496) {               // WVA [kt4][js2][pl2][lane][8] ; A = Winv[k'][jj]
        int t3 = tid - 98304;
        int j = t3 & 7, lane = (t3>>3)&63, pl = (t3>>9)&1, js = (t3>>10)&1, kt = t3>>11;
        int kp = kt*16 + (lane&15);
        int jj = js*32 + (lane>>4)*8 + j;
        float x = WinvG[jj*64 + kp];
        unsigned short hi = bf16_rne(x);
        WVA[t3] = pl ? bf16_rne(x - bf16_f32(hi)) : hi;
    }
}

// ===================== main ADMM kernel — R2 VERBATIM (passing version) ========
__device__ __forceinline__ f32x4 mfma16(short8 a, short8 b, f32x4 c) {
    return __builtin_amdgcn_mfma_f32_16x16x32_bf16(a, b, c, 0, 0, 0);
}

__global__ void __launch_bounds__(TPB, 2)
admm_kernel(const float* __restrict__ lamG, const float* __restrict__ cG,
            const float* __restrict__ beqG, const float* __restrict__ WinvG,
            const unsigned short* __restrict__ MA, const unsigned short* __restrict__ MTA,
            const unsigned short* __restrict__ WVA, float* __restrict__ outG) {
    extern __shared__ char sm[];
    float* waccF = (float*)(sm + LDS_WACC);   // [10][16]
    float* accN  = (float*)(sm + LDS_ACCN);   // [2][16]

    const int t = threadIdx.x;
    const int lane = t & 63;
    const int w = t >> 6;
    const int b = lane & 15;
    const int q = lane >> 4;
    const int kt = w & 3;
    const int dhi = w >> 2;
    const int rt = w;
    const int bbase = blockIdx.x * NBPB;

    float lR[3][3][4];
    float uR[3][3][4];
    float cR[3][4];
    float pbq[3][4];
    unsigned axp[3][6][2];

    for (int i = t; i < 160 + 32; i += TPB) ((float*)(sm + LDS_WACC))[i] = 0.f;

    #pragma unroll
    for (int du = 0; du < 3; ++du) {
        int dof = du*2 + dhi;
        #pragma unroll
        for (int reg = 0; reg < 4; ++reg) {
            int k = kt*16 + q*4 + reg;
            cR[du][reg] = cG[(size_t)(bbase+b)*384 + dof*64 + k];
            #pragma unroll
            for (int m = 0; m < 3; ++m)
                lR[m][du][reg] = lamG[(size_t)(bbase+b)*1152 + m*384 + dof*64 + k];
            float s = 0.f;
            #pragma unroll
            for (int e = 0; e < 5; ++e)
                s += WinvG[(64+e)*64 + k] * beqG[(size_t)(bbase+b)*30 + dof*5 + e];
            pbq[du][reg] = s;
        }
    }

    #pragma unroll
    for (int du = 0; du < 3; ++du) {
        int dof = du*2 + dhi;
        ushort4v hi4, lo4;
        #pragma unroll
        for (int reg = 0; reg < 4; ++reg) {
            unsigned short h = bf16_rne(cR[du][reg]);
            hi4[reg] = h;
            lo4[reg] = bf16_rne(cR[du][reg] - bf16_f32(h));
        }
        int off = (kt*16 + q*4)*2;
        *(ushort4v*)(sm + LDS_PR + ((0*6+dof)*16 + b)*144 + off) = hi4;
        *(ushort4v*)(sm + LDS_PR + ((1*6+dof)*16 + b)*144 + off) = lo4;
    }
    __syncthreads();

    // ---- prologue (dynamic m loop, as in passing R2 build) ----
    for (int m = 0; m < 3; ++m) {
        const float bm = (m==0) ? 0.8f : ((m==1) ? 1.8f : PI_F);
        short8 aMh[2], aMl[2];
        #pragma unroll
        for (int ks = 0; ks < 2; ++ks) {
            aMh[ks] = *(const short8*)(MA + ((((m*8+rt)*2+ks)*2+0)*512 + lane*8));
            aMl[ks] = *(const short8*)(MA + ((((m*8+rt)*2+ks)*2+1)*512 + lane*8));
        }
        #pragma unroll
        for (int dof = 0; dof < 6; ++dof) {
            f32x4 acc = {0.f,0.f,0.f,0.f};
            #pragma unroll
            for (int ks = 0; ks < 2; ++ks) {
                short8 Bh = *(const short8*)(sm + LDS_PR + ((0*6+dof)*16 + b)*144 + (ks*32 + q*8)*2);
                short8 Bl = *(const short8*)(sm + LDS_PR + ((1*6+dof)*16 + b)*144 + (ks*32 + q*8)*2);
                acc = mfma16(aMh[ks], Bh, acc);
                acc = mfma16(aMh[ks], Bl, acc);
                acc = mfma16(aMl[ks], Bh, acc);
            }
            ushort4v wh, wl;
            unsigned short axh[4];
            #pragma unroll
            for (int reg = 0; reg < 4; ++reg) {
                float axn = acc[reg];
                float cl = fminf(bm, fmaxf(-bm, axn));
                float wv = axn + cl;
                unsigned short h = bf16_rne(wv);
                wh[reg] = h;
                wl[reg] = bf16_rne(wv - bf16_f32(h));
                axh[reg] = bf16_rne(axn);
            }
            int off = (rt*16 + q*4)*2;
            *(ushort4v*)(sm + LDS_W0 + ((0*6+dof)*16 + b)*272 + off) = wh;
            *(ushort4v*)(sm + LDS_W0 + ((1*6+dof)*16 + b)*272 + off) = wl;
            axp[m][dof][0] = ((unsigned)axh[1] << 16) | axh[0];
            axp[m][dof][1] = ((unsigned)axh[3] << 16) | axh[2];
        }
        __syncthreads();
        short8 aTh[4], aTl[4];
        #pragma unroll
        for (int ks = 0; ks < 4; ++ks) {
            aTh[ks] = *(const short8*)(MTA + (((((m*4+kt)*4+ks)*2+0)*512) + lane*8));
            aTl[ks] = *(const short8*)(MTA + (((((m*4+kt)*4+ks)*2+1)*512) + lane*8));
        }
        #pragma unroll
        for (int du = 0; du < 3; ++du) {
            int dof = du*2 + dhi;
            f32x4 accH = {0.f,0.f,0.f,0.f};
            #pragma unroll
            for (int ks = 0; ks < 4; ++ks) {
                short8 Bwh = *(const short8*)(sm + LDS_W0 + ((0*6+dof)*16 + b)*272 + (ks*32 + q*8)*2);
                short8 Bwl = *(const short8*)(sm + LDS_W0 + ((1*6+dof)*16 + b)*272 + (ks*32 + q*8)*2);
                accH = mfma16(aTh[ks], Bwh, accH);
                accH = mfma16(aTh[ks], Bwl, accH);
                accH = mfma16(aTl[ks], Bwh, accH);
            }
            #pragma unroll
            for (int reg = 0; reg < 4; ++reg)
                uR[m][du][reg] = lR[m][du][reg] + accH[reg];
        }
        __syncthreads();
    }

    // ==================== 15 iterations ====================
    for (int it = 0; it < NITER; ++it) {
        #pragma unroll
        for (int du = 0; du < 3; ++du) {
            int dof = du*2 + dhi;
            ushort4v hi4, lo4;
            #pragma unroll
            for (int reg = 0; reg < 4; ++reg) {
                float tv = uR[0][du][reg] + uR[1][du][reg] + uR[2][du][reg] + cR[du][reg];
                unsigned short h = bf16_rne(tv);
                hi4[reg] = h;
                lo4[reg] = bf16_rne(tv - bf16_f32(h));
            }
            int off = (kt*16 + q*4)*2;
            *(ushort4v*)(sm + LDS_LN + ((0*6+dof)*16 + b)*144 + off) = hi4;
            *(ushort4v*)(sm + LDS_LN + ((1*6+dof)*16 + b)*144 + off) = lo4;
        }
        __syncthreads();

        {
            short8 aWh[2], aWl[2];
            #pragma unroll
            for (int js = 0; js < 2; ++js) {
                aWh[js] = *(const short8*)(WVA + (((kt*2+js)*2+0)*512 + lane*8));
                aWl[js] = *(const short8*)(WVA + (((kt*2+js)*2+1)*512 + lane*8));
            }
            float cdq = 0.f;
            #pragma unroll
            for (int du = 0; du < 3; ++du) {
                int dof = du*2 + dhi;
                f32x4 acc = {0.f,0.f,0.f,0.f};
                #pragma unroll
                for (int js = 0; js < 2; ++js) {
                    short8 Bh = *(const short8*)(sm + LDS_LN + ((0*6+dof)*16 + b)*144 + (js*32 + q*8)*2);
                    short8 Bl = *(const short8*)(sm + LDS_LN + ((1*6+dof)*16 + b)*144 + (js*32 + q*8)*2);
                    acc = mfma16(aWh[js], Bh, acc);
                    acc = mfma16(aWh[js], Bl, acc);
                    acc = mfma16(aWl[js], Bh, acc);
                }
                ushort4v hi4, lo4;
                #pragma unroll
                for (int reg = 0; reg < 4; ++reg) {
                    float pr = acc[reg] + pbq[du][reg];
                    float cd = pr - cR[du][reg];
                    cdq += cd * cd;
                    cR[du][reg] = pr;
                    unsigned short h = bf16_rne(pr);
                    hi4[reg] = h;
                    lo4[reg] = bf16_rne(pr - bf16_f32(h));
                }
                int off = (kt*16 + q*4)*2;
                *(ushort4v*)(sm + LDS_PR + ((0*6+dof)*16 + b)*144 + off) = hi4;
                *(ushort4v*)(sm + LDS_PR + ((1*6+dof)*16 + b)*144 + off) = lo4;
            }
            cdq += __shfl_xor(cdq, 16, 64);
            cdq += __shfl_xor(cdq, 32, 64);
            if (lane < 16) atomicAdd(&waccF[9*16 + b], cdq);
        }
        __syncthreads();

        for (int m = 0; m < 3; ++m) {
            const float bm = (m==0) ? 0.8f : ((m==1) ? 1.8f : PI_F);
            short8 aMh[2], aMl[2];
            #pragma unroll
            for (int ks = 0; ks < 2; ++ks) {
                aMh[ks] = *(const short8*)(MA + ((((m*8+rt)*2+ks)*2+0)*512 + lane*8));
                aMl[ks] = *(const short8*)(MA + ((((m*8+rt)*2+ks)*2+1)*512 + lane*8));
            }
            float resq = 0.f, sdq = 0.f;
            #pragma unroll
            for (int dof = 0; dof < 6; ++dof) {
                f32x4 acc = {0.f,0.f,0.f,0.f};
                #pragma unroll
                for (int ks = 0; ks < 2; ++ks) {
                    short8 Bh = *(const short8*)(sm + LDS_PR + ((0*6+dof)*16 + b)*144 + (ks*32 + q*8)*2);
                    short8 Bl = *(const short8*)(sm + LDS_PR + ((1*6+dof)*16 + b)*144 + (ks*32 + q*8)*2);
                    acc = mfma16(aMh[ks], Bh, acc);
                    acc = mfma16(aMh[ks], Bl, acc);
                    acc = mfma16(aMl[ks], Bh, acc);
                }
                ushort4v dh, dl, wh, wl;
                unsigned short axh[4];
                unsigned p0 = axp[m][dof][0], p1 = axp[m][dof][1];
                #pragma unroll
                for (int reg = 0; reg < 4; ++reg) {
                    float axn = acc[reg];
                    float axo = bf16_f32((unsigned short)((reg < 2 ? p0 >> (16*reg) : p1 >> (16*(reg-2))) & 0xFFFF));
                    float cl = fminf(bm, fmaxf(-bm, axn));
                    float d  = axn - cl;
                    float wv = axn + cl;
                    resq += d * d;
                    float d1 = fmaxf(0.f, bm - axn) - fmaxf(0.f, bm - axo);
                    float d2 = fmaxf(0.f, bm + axn) - fmaxf(0.f, bm + axo);
                    sdq += d1*d1 + d2*d2;
                    unsigned short h = bf16_rne(d);
                    dh[reg] = h; dl[reg] = bf16_rne(d - bf16_f32(h));
                    h = bf16_rne(wv);
                    wh[reg] = h; wl[reg] = bf16_rne(wv - bf16_f32(h));
                    axh[reg] = bf16_rne(axn);
                }
                int off = (rt*16 + q*4)*2;
                *(ushort4v*)(sm + LDS_D0 + ((0*6+dof)*16 + b)*272 + off) = dh;
                *(ushort4v*)(sm + LDS_D0 + ((1*6+dof)*16 + b)*272 + off) = dl;
                *(ushort4v*)(sm + LDS_W0 + ((0*6+dof)*16 + b)*272 + off) = wh;
                *(ushort4v*)(sm + LDS_W0 + ((1*6+dof)*16 + b)*272 + off) = wl;
                axp[m][dof][0] = ((unsigned)axh[1] << 16) | axh[0];
                axp[m][dof][1] = ((unsigned)axh[3] << 16) | axh[2];
            }
            resq += __shfl_xor(resq, 16, 64); resq += __shfl_xor(resq, 32, 64);
            sdq  += __shfl_xor(sdq, 16, 64);  sdq  += __shfl_xor(sdq, 32, 64);
            if (lane < 16) {
                atomicAdd(&waccF[m*16 + b], resq);
                atomicAdd(&waccF[(3+m)*16 + b], sdq);
            }
            __syncthreads();

            short8 aTh[4], aTl[4];
            #pragma unroll
            for (int ks = 0; ks < 4; ++ks) {
                aTh[ks] = *(const short8*)(MTA + (((((m*4+kt)*4+ks)*2+0)*512) + lane*8));
                aTl[ks] = *(const short8*)(MTA + (((((m*4+kt)*4+ks)*2+1)*512) + lane*8));
            }
            float ldq = 0.f;
            #pragma unroll
            for (int du = 0; du < 3; ++du) {
                int dof = du*2 + dhi;
                f32x4 accD = {0.f,0.f,0.f,0.f};
                f32x4 accH = {0.f,0.f,0.f,0.f};
                #pragma unroll
                for (int ks = 0; ks < 4; ++ks) {
                    short8 Bdh = *(const short8*)(sm + LDS_D0 + ((0*6+dof)*16 + b)*272 + (ks*32 + q*8)*2);
                    short8 Bdl = *(const short8*)(sm + LDS_D0 + ((1*6+dof)*16 + b)*272 + (ks*32 + q*8)*2);
                    short8 Bwh = *(const short8*)(sm + LDS_W0 + ((0*6+dof)*16 + b)*272 + (ks*32 + q*8)*2);
                    short8 Bwl = *(const short8*)(sm + LDS_W0 + ((1*6+dof)*16 + b)*272 + (ks*32 + q*8)*2);
                    accD = mfma16(aTh[ks], Bdh, accD);
                    accD = mfma16(aTh[ks], Bdl, accD);
                    accD = mfma16(aTl[ks], Bdh, accD);
                    accH = mfma16(aTh[ks], Bwh, accH);
                    accH = mfma16(aTh[ks], Bwl, accH);
                    accH = mfma16(aTl[ks], Bwh, accH);
                }
                #pragma unroll
                for (int reg = 0; reg < 4; ++reg) {
                    float delta = accD[reg];
                    float ln2 = lR[m][du][reg] - delta;
                    lR[m][du][reg] = ln2;
                    ldq += delta * delta;
                    uR[m][du][reg] = ln2 + accH[reg];
                }
            }
            ldq += __shfl_xor(ldq, 16, 64); ldq += __shfl_xor(ldq, 32, 64);
            if (lane < 16) atomicAdd(&waccF[(6+m)*16 + b], ldq);
            __syncthreads();
        }

        if (t < 16) {
            float rp = sqrtf(waccF[0*16+t]) + sqrtf(waccF[1*16+t]) + sqrtf(waccF[2*16+t]);
            float fp = sqrtf(waccF[3*16+t]) + sqrtf(waccF[4*16+t]) + sqrtf(waccF[5*16+t])
                     + sqrtf(waccF[6*16+t]) + sqrtf(waccF[7*16+t]) + sqrtf(waccF[8*16+t])
                     + sqrtf(waccF[9*16+t]);
            accN[t]      += fp;
            accN[16 + t] += rp;
            #pragma unroll
            for (int n = 0; n < 10; ++n) waccF[n*16+t] = 0.f;
        }
        __syncthreads();
    }

    #pragma unroll
    for (int du = 0; du < 3; ++du) {
        int dof = du*2 + dhi;
        #pragma unroll
        for (int reg = 0; reg < 4; ++reg) {
            int k = kt*16 + q*4 + reg;
            outG[(size_t)(bbase+b)*384 + dof*64 + k] = cR[du][reg];
        }
    }
    if (t < 16) {
        outG[(size_t)NBATCH*384 + bbase + t]          = accN[t] / 15.f;
        outG[(size_t)NBATCH*384 + NBATCH + bbase + t] = accN[16 + t] / 15.f;
    }
}

extern "C" void kernel_launch(void* const* d_in, const int* in_sizes, int n_in,
                              void* d_out, int out_size, void* d_ws, size_t ws_size,
                              hipStream_t stream) {
    const float* P     = (const float*)d_in[0];
    const float* Pdot  = (const float*)d_in[1];
    const float* Pddot = (const float*)d_in[2];
    const float* lam   = (const float*)d_in[3];
    const float* csamp = (const float*)d_in[4];
    const float* beq   = (const float*)d_in[5];
    float* out = (float*)d_out;

    float* QdG  = (float*)d_ws;            // 4416 floats; overwritten by Winv
    float* WinvG = (float*)d_ws;           // 69*64 floats (same slot)
    unsigned short* MA  = (unsigned short*)((char*)d_ws + WS_FRAG_OFF);
    unsigned short* MTA = MA + 49152;
    unsigned short* WVA = MTA + 49152;

    hipLaunchKernelGGL(build_qd, dim3(18), dim3(256), 0, stream, P, Pdot, Pddot, QdG);
    hipLaunchKernelGGL(invert_qd, dim3(1), dim3(256), 0, stream, QdG, WinvG);
    hipLaunchKernelGGL(pack_frags, dim3(416), dim3(256), 0, stream, P, Pdot, Pddot, WinvG, MA, MTA, WVA);

    hipFuncSetAttribute((const void*)admm_kernel,
                        hipFuncAttributeMaxDynamicSharedMemorySize, LDS_TOTAL);
    hipLaunchKernelGGL(admm_kernel, dim3(NBATCH/NBPB), dim3(TPB), LDS_TOTAL, stream,
                       lam, csamp, beq, WinvG, MA, MTA, WVA, out);
}

// Round 10
// 583.837 us; speedup vs baseline: 7.9912x; 1.3804x over previous
//
#include <hip/hip_runtime.h>
#include <math.h>

#define NITER 15
#define TPB 512
#define NBATCH 4096
#define NBPB 16
#define PI_F 3.14159265358979323846f

typedef __attribute__((ext_vector_type(8))) short short8;
typedef __attribute__((ext_vector_type(4))) float f32x4;
typedef __attribute__((ext_vector_type(4))) unsigned short ushort4v;

// ---------------- LDS layout (bytes) ----------------
#define LDS_D0   0
#define LDS_LN   0
#define LDS_PR   52224
#define LDS_W0   79872
#define LDS_WACC 132096
#define LDS_ACCN 132736
#define LDS_TOTAL 132864

// ---------------- ws layout ----------------
// [0, 17664): QdG (4416 floats) -> overwritten by Winv[69][64]
#define WS_FRAG_OFF 17920

__device__ __forceinline__ unsigned short bf16_rne(float x) {
    unsigned u = __float_as_uint(x);
    unsigned r = (u + 0x7FFFu + ((u >> 16) & 1u)) >> 16;
    return (unsigned short)r;
}
__device__ __forceinline__ float bf16_f32(unsigned short h) {
    return __uint_as_float(((unsigned)h) << 16);
}

// ===================== K0: build Qd entries (fully parallel) =====================
__global__ void build_qd(const float* __restrict__ P, const float* __restrict__ Pd,
                         const float* __restrict__ Pdd, float* __restrict__ QdG) {
    int idx = blockIdx.x*256 + threadIdx.x;
    if (idx < 4096) {
        int i = idx >> 6, j = idx & 63;
        float acc = 0.f;
        for (int r = 0; r < 128; ++r) {
            acc += Pd[r*64+i]*Pd[r*64+j];
            acc += Pdd[r*64+i]*Pdd[r*64+j];
            acc += P[r*64+i]*P[r*64+j];
        }
        QdG[idx] = (i == j ? 1.f : 0.f) + 2.f*acc;
    } else if (idx < 4416) {
        int r2 = idx - 4096;
        int e = r2 >> 6, k = r2 & 63;
        float v = (e == 0) ? P[k] : (e == 1) ? Pd[k] : (e == 2) ? Pdd[k]
                : (e == 3) ? Pd[127*64+k] : Pdd[127*64+k];
        QdG[idx] = v;
    }
}

// ===================== K1: invert Qd — same algorithm/pivots, parallel scan =====
// Pivot selection = first max of |aug[r][p]|, r=p..68 (matches R2 bitwise).
// Fused swap+eliminate: row p <- prow (normalized old row pv);
//   row pv <- srow - srow[p]*prow (srow = old row p); row i -= fi*prow (fi pre-read).
__global__ void invert_qd(const float* __restrict__ QdG, float* __restrict__ Winv) {
    __shared__ float aug[69][140];
    __shared__ float prow[140];
    __shared__ float srow[140];
    __shared__ int   pivS;
    __shared__ float invS;
    const int t = threadIdx.x;  // 256

    for (int idx = t; idx < 69*140; idx += 256) aug[idx/140][idx%140] = 0.f;
    __syncthreads();
    for (int idx = t; idx < 4096; idx += 256) aug[idx >> 6][idx & 63] = QdG[idx];
    for (int idx = t; idx < 320; idx += 256) {
        int e = idx >> 6, k = idx & 63;
        float v = QdG[4096 + idx];
        aug[k][64+e] = v;
        aug[64+e][k] = v;
    }
    for (int i = t; i < 69; i += 256) aug[i][69+i] = 1.f;
    __syncthreads();

    const int gr = t >> 1;        // row 0..127
    const int gh = t & 1;         // col half
    for (int p = 0; p < 69; ++p) {
        // wave-0 parallel argmax over rows p..68 of |aug[r][p]| (first-max tie-break)
        if (t < 64) {
            float bv = -1.f; int bi = p;
            for (int r = p + t; r < 69; r += 64) {
                float a = fabsf(aug[r][p]);
                if (a > bv) { bv = a; bi = r; }
            }
            #pragma unroll
            for (int off = 32; off > 0; off >>= 1) {
                float ov = __shfl_xor(bv, off, 64);
                int   oi = __shfl_xor(bi, off, 64);
                if (ov > bv || (ov == bv && oi < bi)) { bv = ov; bi = oi; }
            }
            if (t == 0) { pivS = bi; invS = 1.f / aug[bi][p]; }
        }
        __syncthreads();
        const int pv = pivS;
        const float inv = invS;
        float fi = 0.f;
        if (gr < 69) fi = aug[gr][p];           // pre-update multiplier for own row
        if (t < 140) {
            prow[t] = aug[pv][t] * inv;          // normalized pivot row (old row pv)
            srow[t] = aug[p][t];                 // old row p (moves to slot pv)
        }
        __syncthreads();
        if (gr < 69) {
            const int cb = gh * 70;
            if (gr == p) {
                #pragma unroll 7
                for (int j = 0; j < 70; ++j) aug[p][cb+j] = prow[cb+j];
            } else if (gr == pv) {
                const float f2 = srow[p];
                #pragma unroll 7
                for (int j = 0; j < 70; ++j) aug[pv][cb+j] = srow[cb+j] - f2 * prow[cb+j];
            } else {
                #pragma unroll 7
                for (int j = 0; j < 70; ++j) aug[gr][cb+j] -= fi * prow[cb+j];
            }
        }
        __syncthreads();
    }
    for (int idx = t; idx < 69*64; idx += 256) Winv[idx] = aug[idx >> 6][69 + (idx & 63)];
}

// ===================== K2: pack bf16 hi/lo MFMA A-fragments =====================
__global__ void pack_frags(const float* __restrict__ P, const float* __restrict__ Pd,
                           const float* __restrict__ Pdd, const float* __restrict__ WinvG,
                           unsigned short* __restrict__ MA, unsigned short* __restrict__ MTA,
                           unsigned short* __restrict__ WVA) {
    int tid = blockIdx.x*256 + threadIdx.x;
    if (tid < 49152) {                       // MA [m][rt8][ks2][pl2][lane][8] ; A = M[r][k]
        int j = tid & 7, lane = (tid>>3)&63, pl = (tid>>9)&1, ks = (tid>>10)&1, rt = (tid>>11)&7, m = tid>>14;
        const float* src = (m==0) ? Pd : ((m==1) ? Pdd : P);
        int r = rt*16 + (lane&15);
        int k = ks*32 + (lane>>4)*8 + j;
        float x = src[r*64+k];
        unsigned short hi = bf16_rne(x);
        MA[tid] = pl ? bf16_rne(x - bf16_f32(hi)) : hi;
    } else if (tid < 98304) {                // MTA [m][kt4][ks4][pl2][lane][8] ; A = M^T[k][r]
        int t2 = tid - 49152;
        int j = t2 & 7, lane = (t2>>3)&63, pl = (t2>>9)&1, ks = (t2>>10)&3, kt = (t2>>12)&3, m = t2>>14;
        const float* src = (m==0) ? Pd : ((m==1) ? Pdd : P);
        int k = kt*16 + (lane&15);
        int r = ks*32 + (lane>>4)*8 + j;
        float x = src[r*64+k];
        unsigned short hi = bf16_rne(x);
        MTA[t2] = pl ? bf16_rne(x - bf16_f32(hi)) : hi;
    } else if (tid < 106496) {               // WVA [kt4][js2][pl2][lane][8] ; A = Winv[k'][jj]
        int t3 = tid - 98304;
        int j = t3 & 7, lane = (t3>>3)&63, pl = (t3>>9)&1, js = (t3>>10)&1, kt = t3>>11;
        int kp = kt*16 + (lane&15);
        int jj = js*32 + (lane>>4)*8 + j;
        float x = WinvG[jj*64 + kp];
        unsigned short hi = bf16_rne(x);
        WVA[t3] = pl ? bf16_rne(x - bf16_f32(hi)) : hi;
    }
}

// ===================== main ADMM kernel — R9 VERBATIM (passing) ================
__device__ __forceinline__ f32x4 mfma16(short8 a, short8 b, f32x4 c) {
    return __builtin_amdgcn_mfma_f32_16x16x32_bf16(a, b, c, 0, 0, 0);
}

__global__ void __launch_bounds__(TPB, 2)
admm_kernel(const float* __restrict__ lamG, const float* __restrict__ cG,
            const float* __restrict__ beqG, const float* __restrict__ WinvG,
            const unsigned short* __restrict__ MA, const unsigned short* __restrict__ MTA,
            const unsigned short* __restrict__ WVA, float* __restrict__ outG) {
    extern __shared__ char sm[];
    float* waccF = (float*)(sm + LDS_WACC);   // [10][16]
    float* accN  = (float*)(sm + LDS_ACCN);   // [2][16]

    const int t = threadIdx.x;
    const int lane = t & 63;
    const int w = t >> 6;
    const int b = lane & 15;
    const int q = lane >> 4;
    const int kt = w & 3;
    const int dhi = w >> 2;
    const int rt = w;
    const int bbase = blockIdx.x * NBPB;

    float lR[3][3][4];
    float uR[3][3][4];
    float cR[3][4];
    float pbq[3][4];
    unsigned axp[3][6][2];

    for (int i = t; i < 160 + 32; i += TPB) ((float*)(sm + LDS_WACC))[i] = 0.f;

    #pragma unroll
    for (int du = 0; du < 3; ++du) {
        int dof = du*2 + dhi;
        #pragma unroll
        for (int reg = 0; reg < 4; ++reg) {
            int k = kt*16 + q*4 + reg;
            cR[du][reg] = cG[(size_t)(bbase+b)*384 + dof*64 + k];
            #pragma unroll
            for (int m = 0; m < 3; ++m)
                lR[m][du][reg] = lamG[(size_t)(bbase+b)*1152 + m*384 + dof*64 + k];
            float s = 0.f;
            #pragma unroll
            for (int e = 0; e < 5; ++e)
                s += WinvG[(64+e)*64 + k] * beqG[(size_t)(bbase+b)*30 + dof*5 + e];
            pbq[du][reg] = s;
        }
    }

    #pragma unroll
    for (int du = 0; du < 3; ++du) {
        int dof = du*2 + dhi;
        ushort4v hi4, lo4;
        #pragma unroll
        for (int reg = 0; reg < 4; ++reg) {
            unsigned short h = bf16_rne(cR[du][reg]);
            hi4[reg] = h;
            lo4[reg] = bf16_rne(cR[du][reg] - bf16_f32(h));
        }
        int off = (kt*16 + q*4)*2;
        *(ushort4v*)(sm + LDS_PR + ((0*6+dof)*16 + b)*144 + off) = hi4;
        *(ushort4v*)(sm + LDS_PR + ((1*6+dof)*16 + b)*144 + off) = lo4;
    }
    __syncthreads();

    // ---- prologue (dynamic m loop — do NOT unroll; unrolling miscompiles) ----
    for (int m = 0; m < 3; ++m) {
        const float bm = (m==0) ? 0.8f : ((m==1) ? 1.8f : PI_F);
        short8 aMh[2], aMl[2];
        #pragma unroll
        for (int ks = 0; ks < 2; ++ks) {
            aMh[ks] = *(const short8*)(MA + ((((m*8+rt)*2+ks)*2+0)*512 + lane*8));
            aMl[ks] = *(const short8*)(MA + ((((m*8+rt)*2+ks)*2+1)*512 + lane*8));
        }
        #pragma unroll
        for (int dof = 0; dof < 6; ++dof) {
            f32x4 acc = {0.f,0.f,0.f,0.f};
            #pragma unroll
            for (int ks = 0; ks < 2; ++ks) {
                short8 Bh = *(const short8*)(sm + LDS_PR + ((0*6+dof)*16 + b)*144 + (ks*32 + q*8)*2);
                short8 Bl = *(const short8*)(sm + LDS_PR + ((1*6+dof)*16 + b)*144 + (ks*32 + q*8)*2);
                acc = mfma16(aMh[ks], Bh, acc);
                acc = mfma16(aMh[ks], Bl, acc);
                acc = mfma16(aMl[ks], Bh, acc);
            }
            ushort4v wh, wl;
            unsigned short axh[4];
            #pragma unroll
            for (int reg = 0; reg < 4; ++reg) {
                float axn = acc[reg];
                float cl = fminf(bm, fmaxf(-bm, axn));
                float wv = axn + cl;
                unsigned short h = bf16_rne(wv);
                wh[reg] = h;
                wl[reg] = bf16_rne(wv - bf16_f32(h));
                axh[reg] = bf16_rne(axn);
            }
            int off = (rt*16 + q*4)*2;
            *(ushort4v*)(sm + LDS_W0 + ((0*6+dof)*16 + b)*272 + off) = wh;
            *(ushort4v*)(sm + LDS_W0 + ((1*6+dof)*16 + b)*272 + off) = wl;
            axp[m][dof][0] = ((unsigned)axh[1] << 16) | axh[0];
            axp[m][dof][1] = ((unsigned)axh[3] << 16) | axh[2];
        }
        __syncthreads();
        short8 aTh[4], aTl[4];
        #pragma unroll
        for (int ks = 0; ks < 4; ++ks) {
            aTh[ks] = *(const short8*)(MTA + (((((m*4+kt)*4+ks)*2+0)*512) + lane*8));
            aTl[ks] = *(const short8*)(MTA + (((((m*4+kt)*4+ks)*2+1)*512) + lane*8));
        }
        #pragma unroll
        for (int du = 0; du < 3; ++du) {
            int dof = du*2 + dhi;
            f32x4 accH = {0.f,0.f,0.f,0.f};
            #pragma unroll
            for (int ks = 0; ks < 4; ++ks) {
                short8 Bwh = *(const short8*)(sm + LDS_W0 + ((0*6+dof)*16 + b)*272 + (ks*32 + q*8)*2);
                short8 Bwl = *(const short8*)(sm + LDS_W0 + ((1*6+dof)*16 + b)*272 + (ks*32 + q*8)*2);
                accH = mfma16(aTh[ks], Bwh, accH);
                accH = mfma16(aTh[ks], Bwl, accH);
                accH = mfma16(aTl[ks], Bwh, accH);
            }
            #pragma unroll
            for (int reg = 0; reg < 4; ++reg)
                uR[m][du][reg] = lR[m][du][reg] + accH[reg];
        }
        __syncthreads();
    }

    // ==================== 15 iterations ====================
    for (int it = 0; it < NITER; ++it) {
        #pragma unroll
        for (int du = 0; du < 3; ++du) {
            int dof = du*2 + dhi;
            ushort4v hi4, lo4;
            #pragma unroll
            for (int reg = 0; reg < 4; ++reg) {
                float tv = uR[0][du][reg] + uR[1][du][reg] + uR[2][du][reg] + cR[du][reg];
                unsigned short h = bf16_rne(tv);
                hi4[reg] = h;
                lo4[reg] = bf16_rne(tv - bf16_f32(h));
            }
            int off = (kt*16 + q*4)*2;
            *(ushort4v*)(sm + LDS_LN + ((0*6+dof)*16 + b)*144 + off) = hi4;
            *(ushort4v*)(sm + LDS_LN + ((1*6+dof)*16 + b)*144 + off) = lo4;
        }
        __syncthreads();

        {
            short8 aWh[2], aWl[2];
            #pragma unroll
            for (int js = 0; js < 2; ++js) {
                aWh[js] = *(const short8*)(WVA + (((kt*2+js)*2+0)*512 + lane*8));
                aWl[js] = *(const short8*)(WVA + (((kt*2+js)*2+1)*512 + lane*8));
            }
            float cdq = 0.f;
            #pragma unroll
            for (int du = 0; du < 3; ++du) {
                int dof = du*2 + dhi;
                f32x4 acc = {0.f,0.f,0.f,0.f};
                #pragma unroll
                for (int js = 0; js < 2; ++js) {
                    short8 Bh = *(const short8*)(sm + LDS_LN + ((0*6+dof)*16 + b)*144 + (js*32 + q*8)*2);
                    short8 Bl = *(const short8*)(sm + LDS_LN + ((1*6+dof)*16 + b)*144 + (js*32 + q*8)*2);
                    acc = mfma16(aWh[js], Bh, acc);
                    acc = mfma16(aWh[js], Bl, acc);
                    acc = mfma16(aWl[js], Bh, acc);
                }
                ushort4v hi4, lo4;
                #pragma unroll
                for (int reg = 0; reg < 4; ++reg) {
                    float pr = acc[reg] + pbq[du][reg];
                    float cd = pr - cR[du][reg];
                    cdq += cd * cd;
                    cR[du][reg] = pr;
                    unsigned short h = bf16_rne(pr);
                    hi4[reg] = h;
                    lo4[reg] = bf16_rne(pr - bf16_f32(h));
                }
                int off = (kt*16 + q*4)*2;
                *(ushort4v*)(sm + LDS_PR + ((0*6+dof)*16 + b)*144 + off) = hi4;
                *(ushort4v*)(sm + LDS_PR + ((1*6+dof)*16 + b)*144 + off) = lo4;
            }
            cdq += __shfl_xor(cdq, 16, 64);
            cdq += __shfl_xor(cdq, 32, 64);
            if (lane < 16) atomicAdd(&waccF[9*16 + b], cdq);
        }
        __syncthreads();

        for (int m = 0; m < 3; ++m) {
            const float bm = (m==0) ? 0.8f : ((m==1) ? 1.8f : PI_F);
            short8 aMh[2], aMl[2];
            #pragma unroll
            for (int ks = 0; ks < 2; ++ks) {
                aMh[ks] = *(const short8*)(MA + ((((m*8+rt)*2+ks)*2+0)*512 + lane*8));
                aMl[ks] = *(const short8*)(MA + ((((m*8+rt)*2+ks)*2+1)*512 + lane*8));
            }
            float resq = 0.f, sdq = 0.f;
            #pragma unroll
            for (int dof = 0; dof < 6; ++dof) {
                f32x4 acc = {0.f,0.f,0.f,0.f};
                #pragma unroll
                for (int ks = 0; ks < 2; ++ks) {
                    short8 Bh = *(const short8*)(sm + LDS_PR + ((0*6+dof)*16 + b)*144 + (ks*32 + q*8)*2);
                    short8 Bl = *(const short8*)(sm + LDS_PR + ((1*6+dof)*16 + b)*144 + (ks*32 + q*8)*2);
                    acc = mfma16(aMh[ks], Bh, acc);
                    acc = mfma16(aMh[ks], Bl, acc);
                    acc = mfma16(aMl[ks], Bh, acc);
                }
                ushort4v dh, dl, wh, wl;
                unsigned short axh[4];
                unsigned p0 = axp[m][dof][0], p1 = axp[m][dof][1];
                #pragma unroll
                for (int reg = 0; reg < 4; ++reg) {
                    float axn = acc[reg];
                    float axo = bf16_f32((unsigned short)((reg < 2 ? p0 >> (16*reg) : p1 >> (16*(reg-2))) & 0xFFFF));
                    float cl = fminf(bm, fmaxf(-bm, axn));
                    float d  = axn - cl;
                    float wv = axn + cl;
                    resq += d * d;
                    float d1 = fmaxf(0.f, bm - axn) - fmaxf(0.f, bm - axo);
                    float d2 = fmaxf(0.f, bm + axn) - fmaxf(0.f, bm + axo);
                    sdq += d1*d1 + d2*d2;
                    unsigned short h = bf16_rne(d);
                    dh[reg] = h; dl[reg] = bf16_rne(d - bf16_f32(h));
                    h = bf16_rne(wv);
                    wh[reg] = h; wl[reg] = bf16_rne(wv - bf16_f32(h));
                    axh[reg] = bf16_rne(axn);
                }
                int off = (rt*16 + q*4)*2;
                *(ushort4v*)(sm + LDS_D0 + ((0*6+dof)*16 + b)*272 + off) = dh;
                *(ushort4v*)(sm + LDS_D0 + ((1*6+dof)*16 + b)*272 + off) = dl;
                *(ushort4v*)(sm + LDS_W0 + ((0*6+dof)*16 + b)*272 + off) = wh;
                *(ushort4v*)(sm + LDS_W0 + ((1*6+dof)*16 + b)*272 + off) = wl;
                axp[m][dof][0] = ((unsigned)axh[1] << 16) | axh[0];
                axp[m][dof][1] = ((unsigned)axh[3] << 16) | axh[2];
            }
            resq += __shfl_xor(resq, 16, 64); resq += __shfl_xor(resq, 32, 64);
            sdq  += __shfl_xor(sdq, 16, 64);  sdq  += __shfl_xor(sdq, 32, 64);
            if (lane < 16) {
                atomicAdd(&waccF[m*16 + b], resq);
                atomicAdd(&waccF[(3+m)*16 + b], sdq);
            }
            __syncthreads();

            short8 aTh[4], aTl[4];
            #pragma unroll
            for (int ks = 0; ks < 4; ++ks) {
                aTh[ks] = *(const short8*)(MTA + (((((m*4+kt)*4+ks)*2+0)*512) + lane*8));
                aTl[ks] = *(const short8*)(MTA + (((((m*4+kt)*4+ks)*2+1)*512) + lane*8));
            }
            float ldq = 0.f;
            #pragma unroll
            for (int du = 0; du < 3; ++du) {
                int dof = du*2 + dhi;
                f32x4 accD = {0.f,0.f,0.f,0.f};
                f32x4 accH = {0.f,0.f,0.f,0.f};
                #pragma unroll
                for (int ks = 0; ks < 4; ++ks) {
                    short8 Bdh = *(const short8*)(sm + LDS_D0 + ((0*6+dof)*16 + b)*272 + (ks*32 + q*8)*2);
                    short8 Bdl = *(const short8*)(sm + LDS_D0 + ((1*6+dof)*16 + b)*272 + (ks*32 + q*8)*2);
                    short8 Bwh = *(const short8*)(sm + LDS_W0 + ((0*6+dof)*16 + b)*272 + (ks*32 + q*8)*2);
                    short8 Bwl = *(const short8*)(sm + LDS_W0 + ((1*6+dof)*16 + b)*272 + (ks*32 + q*8)*2);
                    accD = mfma16(aTh[ks], Bdh, accD);
                    accD = mfma16(aTh[ks], Bdl, accD);
                    accD = mfma16(aTl[ks], Bdh, accD);
                    accH = mfma16(aTh[ks], Bwh, accH);
                    accH = mfma16(aTh[ks], Bwl, accH);
                    accH = mfma16(aTl[ks], Bwh, accH);
                }
                #pragma unroll
                for (int reg = 0; reg < 4; ++reg) {
                    float delta = accD[reg];
                    float ln2 = lR[m][du][reg] - delta;
                    lR[m][du][reg] = ln2;
                    ldq += delta * delta;
                    uR[m][du][reg] = ln2 + accH[reg];
                }
            }
            ldq += __shfl_xor(ldq, 16, 64); ldq += __shfl_xor(ldq, 32, 64);
            if (lane < 16) atomicAdd(&waccF[(6+m)*16 + b], ldq);
            __syncthreads();
        }

        if (t < 16) {
            float rp = sqrtf(waccF[0*16+t]) + sqrtf(waccF[1*16+t]) + sqrtf(waccF[2*16+t]);
            float fp = sqrtf(waccF[3*16+t]) + sqrtf(waccF[4*16+t]) + sqrtf(waccF[5*16+t])
                     + sqrtf(waccF[6*16+t]) + sqrtf(waccF[7*16+t]) + sqrtf(waccF[8*16+t])
                     + sqrtf(waccF[9*16+t]);
            accN[t]      += fp;
            accN[16 + t] += rp;
            #pragma unroll
            for (int n = 0; n < 10; ++n) waccF[n*16+t] = 0.f;
        }
        __syncthreads();
    }

    #pragma unroll
    for (int du = 0; du < 3; ++du) {
        int dof = du*2 + dhi;
        #pragma unroll
        for (int reg = 0; reg < 4; ++reg) {
            int k = kt*16 + q*4 + reg;
            outG[(size_t)(bbase+b)*384 + dof*64 + k] = cR[du][reg];
        }
    }
    if (t < 16) {
        outG[(size_t)NBATCH*384 + bbase + t]          = accN[t] / 15.f;
        outG[(size_t)NBATCH*384 + NBATCH + bbase + t] = accN[16 + t] / 15.f;
    }
}

extern "C" void kernel_launch(void* const* d_in, const int* in_sizes, int n_in,
                              void* d_out, int out_size, void* d_ws, size_t ws_size,
                              hipStream_t stream) {
    const float* P     = (const float*)d_in[0];
    const float* Pdot  = (const float*)d_in[1];
    const float* Pddot = (const float*)d_in[2];
    const float* lam   = (const float*)d_in[3];
    const float* csamp = (const float*)d_in[4];
    const float* beq   = (const float*)d_in[5];
    float* out = (float*)d_out;

    float* QdG  = (float*)d_ws;            // 4416 floats; overwritten by Winv
    float* WinvG = (float*)d_ws;           // 69*64 floats (same slot)
    unsigned short* MA  = (unsigned short*)((char*)d_ws + WS_FRAG_OFF);
    unsigned short* MTA = MA + 49152;
    unsigned short* WVA = MTA + 49152;

    hipLaunchKernelGGL(build_qd, dim3(18), dim3(256), 0, stream, P, Pdot, Pddot, QdG);
    hipLaunchKernelGGL(invert_qd, dim3(1), dim3(256), 0, stream, QdG, WinvG);
    hipLaunchKernelGGL(pack_frags, dim3(416), dim3(256), 0, stream, P, Pdot, Pddot, WinvG, MA, MTA, WVA);

    hipFuncSetAttribute((const void*)admm_kernel,
                        hipFuncAttributeMaxDynamicSharedMemorySize, LDS_TOTAL);
    hipLaunchKernelGGL(admm_kernel, dim3(NBATCH/NBPB), dim3(TPB), LDS_TOTAL, stream,
                       lam, csamp, beq, WinvG, MA, MTA, WVA, out);
}

// Round 12
// 550.825 us; speedup vs baseline: 8.4701x; 1.0599x over previous
//
#include <hip/hip_runtime.h>
#include <math.h>

#define NITER 15
#define TPB 512
#define NBATCH 4096
#define NBPB 16
#define PI_F 3.14159265358979323846f

typedef __attribute__((ext_vector_type(8))) short short8;
typedef __attribute__((ext_vector_type(4))) float f32x4;
typedef __attribute__((ext_vector_type(4))) unsigned short ushort4v;

// ---------------- LDS layout (bytes) ----------------
#define LDS_D0   0
#define LDS_LN   0
#define LDS_PR   52224
#define LDS_W0   79872
#define LDS_WACC 132096
#define LDS_ACCN 132736
#define LDS_HS   132864            // hS: [512 threads][13 floats] (12 used + 1 pad; 13 coprime 32 -> conflict-free)
#define LDS_TOTAL (132864 + 512*13*4)   // 159488 <= 163840

// ---------------- ws layout ----------------
// [0, 17664): QdG (4416 floats) -> overwritten by Winv[69][64]
#define WS_FRAG_OFF 17920

__device__ __forceinline__ unsigned short bf16_rne(float x) {
    unsigned u = __float_as_uint(x);
    unsigned r = (u + 0x7FFFu + ((u >> 16) & 1u)) >> 16;
    return (unsigned short)r;
}
__device__ __forceinline__ float bf16_f32(unsigned short h) {
    return __uint_as_float(((unsigned)h) << 16);
}

// ===================== K0: build Qd entries (fully parallel) =====================
__global__ void build_qd(const float* __restrict__ P, const float* __restrict__ Pd,
                         const float* __restrict__ Pdd, float* __restrict__ QdG) {
    int idx = blockIdx.x*256 + threadIdx.x;
    if (idx < 4096) {
        int i = idx >> 6, j = idx & 63;
        float acc = 0.f;
        for (int r = 0; r < 128; ++r) {
            acc += Pd[r*64+i]*Pd[r*64+j];
            acc += Pdd[r*64+i]*Pdd[r*64+j];
            acc += P[r*64+i]*P[r*64+j];
        }
        QdG[idx] = (i == j ? 1.f : 0.f) + 2.f*acc;
    } else if (idx < 4416) {
        int r2 = idx - 4096;
        int e = r2 >> 6, k = r2 & 63;
        float v = (e == 0) ? P[k] : (e == 1) ? Pd[k] : (e == 2) ? Pdd[k]
                : (e == 3) ? Pd[127*64+k] : Pdd[127*64+k];
        QdG[idx] = v;
    }
}

// ===================== K1: invert Qd — parallel argmax + fused swap (R10, green) ==
__global__ void invert_qd(const float* __restrict__ QdG, float* __restrict__ Winv) {
    __shared__ float aug[69][140];
    __shared__ float prow[140];
    __shared__ float srow[140];
    __shared__ int   pivS;
    __shared__ float invS;
    const int t = threadIdx.x;  // 256

    for (int idx = t; idx < 69*140; idx += 256) aug[idx/140][idx%140] = 0.f;
    __syncthreads();
    for (int idx = t; idx < 4096; idx += 256) aug[idx >> 6][idx & 63] = QdG[idx];
    for (int idx = t; idx < 320; idx += 256) {
        int e = idx >> 6, k = idx & 63;
        float v = QdG[4096 + idx];
        aug[k][64+e] = v;
        aug[64+e][k] = v;
    }
    for (int i = t; i < 69; i += 256) aug[i][69+i] = 1.f;
    __syncthreads();

    const int gr = t >> 1;        // row 0..127
    const int gh = t & 1;         // col half
    for (int p = 0; p < 69; ++p) {
        if (t < 64) {
            float bv = -1.f; int bi = p;
            for (int r = p + t; r < 69; r += 64) {
                float a = fabsf(aug[r][p]);
                if (a > bv) { bv = a; bi = r; }
            }
            #pragma unroll
            for (int off = 32; off > 0; off >>= 1) {
                float ov = __shfl_xor(bv, off, 64);
                int   oi = __shfl_xor(bi, off, 64);
                if (ov > bv || (ov == bv && oi < bi)) { bv = ov; bi = oi; }
            }
            if (t == 0) { pivS = bi; invS = 1.f / aug[bi][p]; }
        }
        __syncthreads();
        const int pv = pivS;
        const float inv = invS;
        float fi = 0.f;
        if (gr < 69) fi = aug[gr][p];
        if (t < 140) {
            prow[t] = aug[pv][t] * inv;
            srow[t] = aug[p][t];
        }
        __syncthreads();
        if (gr < 69) {
            const int cb = gh * 70;
            if (gr == p) {
                #pragma unroll 7
                for (int j = 0; j < 70; ++j) aug[p][cb+j] = prow[cb+j];
            } else if (gr == pv) {
                const float f2 = srow[p];
                #pragma unroll 7
                for (int j = 0; j < 70; ++j) aug[pv][cb+j] = srow[cb+j] - f2 * prow[cb+j];
            } else {
                #pragma unroll 7
                for (int j = 0; j < 70; ++j) aug[gr][cb+j] -= fi * prow[cb+j];
            }
        }
        __syncthreads();
    }
    for (int idx = t; idx < 69*64; idx += 256) Winv[idx] = aug[idx >> 6][69 + (idx & 63)];
}

// ===================== K2: pack bf16 hi/lo MFMA A-fragments =====================
__global__ void pack_frags(const float* __restrict__ P, const float* __restrict__ Pd,
                           const float* __restrict__ Pdd, const float* __restrict__ WinvG,
                           unsigned short* __restrict__ MA, unsigned short* __restrict__ MTA,
                           unsigned short* __restrict__ WVA) {
    int tid = blockIdx.x*256 + threadIdx.x;
    if (tid < 49152) {                       // MA [m][rt8][ks2][pl2][lane][8] ; A = M[r][k]
        int j = tid & 7, lane = (tid>>3)&63, pl = (tid>>9)&1, ks = (tid>>10)&1, rt = (tid>>11)&7, m = tid>>14;
        const float* src = (m==0) ? Pd : ((m==1) ? Pdd : P);
        int r = rt*16 + (lane&15);
        int k = ks*32 + (lane>>4)*8 + j;
        float x = src[r*64+k];
        unsigned short hi = bf16_rne(x);
        MA[tid] = pl ? bf16_rne(x - bf16_f32(hi)) : hi;
    } else if (tid < 98304) {                // MTA [m][kt4][ks4][pl2][lane][8] ; A = M^T[k][r]
        int t2 = tid - 49152;
        int j = t2 & 7, lane = (t2>>3)&63, pl = (t2>>9)&1, ks = (t2>>10)&3, kt = (t2>>12)&3, m = t2>>14;
        const float* src = (m==0) ? Pd : ((m==1) ? Pdd : P);
        int k = kt*16 + (lane&15);
        int r = ks*32 + (lane>>4)*8 + j;
        float x = src[r*64+k];
        unsigned short hi = bf16_rne(x);
        MTA[t2] = pl ? bf16_rne(x - bf16_f32(hi)) : hi;
    } else if (tid < 106496) {               // WVA [kt4][js2][pl2][lane][8] ; A = Winv[k'][jj]
        int t3 = tid - 98304;
        int j = t3 & 7, lane = (t3>>3)&63, pl = (t3>>9)&1, js = (t3>>10)&1, kt = t3>>11;
        int kp = kt*16 + (lane&15);
        int jj = js*32 + (lane>>4)*8 + j;
        float x = WinvG[jj*64 + kp];
        unsigned short hi = bf16_rne(x);
        WVA[t3] = pl ? bf16_rne(x - bf16_f32(hi)) : hi;
    }
}

// ===================== main ADMM kernel =====================
__device__ __forceinline__ f32x4 mfma16(short8 a, short8 b, f32x4 c) {
    return __builtin_amdgcn_mfma_f32_16x16x32_bf16(a, b, c, 0, 0, 0);
}

// State residency rule (hard-won, R4-R11): persistent accumulators must NOT be
// promoted to VGPRs — register-resident variants miscompile (build-varying O(1)
// errors). lR stays scratch (dynamic m); h-sum lives in per-thread LDS slots.
__global__ void __launch_bounds__(TPB, 2)
admm_kernel(const float* __restrict__ lamG, const float* __restrict__ cG,
            const float* __restrict__ beqG, const float* __restrict__ WinvG,
            const unsigned short* __restrict__ MA, const unsigned short* __restrict__ MTA,
            const unsigned short* __restrict__ WVA, float* __restrict__ outG) {
    extern __shared__ char sm[];
    float* waccF = (float*)(sm + LDS_WACC);   // [10][16]
    float* accN  = (float*)(sm + LDS_ACCN);   // [2][16]
    float* hSL   = (float*)(sm + LDS_HS);     // [512][13] per-thread h-sum slots

    const int t = threadIdx.x;
    const int lane = t & 63;
    const int w = t >> 6;
    const int b = lane & 15;
    const int q = lane >> 4;
    const int kt = w & 3;
    const int dhi = w >> 2;
    const int rt = w;
    const int bbase = blockIdx.x * NBPB;
    const int hbase = t * 13;

    float lR[3][3][4];      // per-m dual (scratch via dynamic m — proven shape)
    float cR[3][4];
    float pbq[3][4];
    unsigned axp[3][6][2];

    for (int i = t; i < 160 + 32; i += TPB) ((float*)(sm + LDS_WACC))[i] = 0.f;
    #pragma unroll
    for (int i = 0; i < 12; ++i) hSL[hbase + i] = 0.f;   // own slots only

    #pragma unroll
    for (int du = 0; du < 3; ++du) {
        int dof = du*2 + dhi;
        #pragma unroll
        for (int reg = 0; reg < 4; ++reg) {
            int k = kt*16 + q*4 + reg;
            cR[du][reg] = cG[(size_t)(bbase+b)*384 + dof*64 + k];
            #pragma unroll
            for (int m = 0; m < 3; ++m)
                lR[m][du][reg] = lamG[(size_t)(bbase+b)*1152 + m*384 + dof*64 + k];
            float s = 0.f;
            #pragma unroll
            for (int e = 0; e < 5; ++e)
                s += WinvG[(64+e)*64 + k] * beqG[(size_t)(bbase+b)*30 + dof*5 + e];
            pbq[du][reg] = s;
        }
    }

    #pragma unroll
    for (int du = 0; du < 3; ++du) {
        int dof = du*2 + dhi;
        ushort4v hi4, lo4;
        #pragma unroll
        for (int reg = 0; reg < 4; ++reg) {
            unsigned short h = bf16_rne(cR[du][reg]);
            hi4[reg] = h;
            lo4[reg] = bf16_rne(cR[du][reg] - bf16_f32(h));
        }
        int off = (kt*16 + q*4)*2;
        *(ushort4v*)(sm + LDS_PR + ((0*6+dof)*16 + b)*144 + off) = hi4;
        *(ushort4v*)(sm + LDS_PR + ((1*6+dof)*16 + b)*144 + off) = lo4;
    }
    __syncthreads();

    // ---- prologue (dynamic m loop — keep dynamic; register-promoted variants miscompile) ----
    for (int m = 0; m < 3; ++m) {
        const float bm = (m==0) ? 0.8f : ((m==1) ? 1.8f : PI_F);
        short8 aMh[2], aMl[2];
        #pragma unroll
        for (int ks = 0; ks < 2; ++ks) {
            aMh[ks] = *(const short8*)(MA + ((((m*8+rt)*2+ks)*2+0)*512 + lane*8));
            aMl[ks] = *(const short8*)(MA + ((((m*8+rt)*2+ks)*2+1)*512 + lane*8));
        }
        #pragma unroll
        for (int dof = 0; dof < 6; ++dof) {
            f32x4 acc = {0.f,0.f,0.f,0.f};
            #pragma unroll
            for (int ks = 0; ks < 2; ++ks) {
                short8 Bh = *(const short8*)(sm + LDS_PR + ((0*6+dof)*16 + b)*144 + (ks*32 + q*8)*2);
                short8 Bl = *(const short8*)(sm + LDS_PR + ((1*6+dof)*16 + b)*144 + (ks*32 + q*8)*2);
                acc = mfma16(aMh[ks], Bh, acc);
                acc = mfma16(aMh[ks], Bl, acc);
                acc = mfma16(aMl[ks], Bh, acc);
            }
            ushort4v wh, wl;
            unsigned short axh[4];
            #pragma unroll
            for (int reg = 0; reg < 4; ++reg) {
                float axn = acc[reg];
                float cl = fminf(bm, fmaxf(-bm, axn));
                float wv = axn + cl;
                unsigned short h = bf16_rne(wv);
                wh[reg] = h;
                wl[reg] = bf16_rne(wv - bf16_f32(h));
                axh[reg] = bf16_rne(axn);
            }
            int off = (rt*16 + q*4)*2;
            *(ushort4v*)(sm + LDS_W0 + ((0*6+dof)*16 + b)*272 + off) = wh;
            *(ushort4v*)(sm + LDS_W0 + ((1*6+dof)*16 + b)*272 + off) = wl;
            axp[m][dof][0] = ((unsigned)axh[1] << 16) | axh[0];
            axp[m][dof][1] = ((unsigned)axh[3] << 16) | axh[2];
        }
        __syncthreads();
        short8 aTh[4], aTl[4];
        #pragma unroll
        for (int ks = 0; ks < 4; ++ks) {
            aTh[ks] = *(const short8*)(MTA + (((((m*4+kt)*4+ks)*2+0)*512) + lane*8));
            aTl[ks] = *(const short8*)(MTA + (((((m*4+kt)*4+ks)*2+1)*512) + lane*8));
        }
        #pragma unroll
        for (int du = 0; du < 3; ++du) {
            int dof = du*2 + dhi;
            f32x4 accH = {0.f,0.f,0.f,0.f};
            #pragma unroll
            for (int ks = 0; ks < 4; ++ks) {
                short8 Bwh = *(const short8*)(sm + LDS_W0 + ((0*6+dof)*16 + b)*272 + (ks*32 + q*8)*2);
                short8 Bwl = *(const short8*)(sm + LDS_W0 + ((1*6+dof)*16 + b)*272 + (ks*32 + q*8)*2);
                accH = mfma16(aTh[ks], Bwh, accH);
                accH = mfma16(aTh[ks], Bwl, accH);
                accH = mfma16(aTl[ks], Bwh, accH);
            }
            #pragma unroll
            for (int reg = 0; reg < 4; ++reg)
                hSL[hbase + du*4 + reg] += accH[reg];
        }
        __syncthreads();
    }

    // ==================== 15 iterations ====================
    for (int it = 0; it < NITER; ++it) {
        // ---- phase A: t = sum_m l_m + sum_m h_m + c ----
        #pragma unroll
        for (int du = 0; du < 3; ++du) {
            int dof = du*2 + dhi;
            ushort4v hi4, lo4;
            #pragma unroll
            for (int reg = 0; reg < 4; ++reg) {
                float tv = lR[0][du][reg] + lR[1][du][reg] + lR[2][du][reg]
                         + hSL[hbase + du*4 + reg] + cR[du][reg];
                unsigned short h = bf16_rne(tv);
                hi4[reg] = h;
                lo4[reg] = bf16_rne(tv - bf16_f32(h));
            }
            int off = (kt*16 + q*4)*2;
            *(ushort4v*)(sm + LDS_LN + ((0*6+dof)*16 + b)*144 + off) = hi4;
            *(ushort4v*)(sm + LDS_LN + ((1*6+dof)*16 + b)*144 + off) = lo4;
        }
        __syncthreads();

        // ---- phase B: primal ----
        {
            short8 aWh[2], aWl[2];
            #pragma unroll
            for (int js = 0; js < 2; ++js) {
                aWh[js] = *(const short8*)(WVA + (((kt*2+js)*2+0)*512 + lane*8));
                aWl[js] = *(const short8*)(WVA + (((kt*2+js)*2+1)*512 + lane*8));
            }
            float cdq = 0.f;
            #pragma unroll
            for (int du = 0; du < 3; ++du) {
                int dof = du*2 + dhi;
                f32x4 acc = {0.f,0.f,0.f,0.f};
                #pragma unroll
                for (int js = 0; js < 2; ++js) {
                    short8 Bh = *(const short8*)(sm + LDS_LN + ((0*6+dof)*16 + b)*144 + (js*32 + q*8)*2);
                    short8 Bl = *(const short8*)(sm + LDS_LN + ((1*6+dof)*16 + b)*144 + (js*32 + q*8)*2);
                    acc = mfma16(aWh[js], Bh, acc);
                    acc = mfma16(aWh[js], Bl, acc);
                    acc = mfma16(aWl[js], Bh, acc);
                }
                ushort4v hi4, lo4;
                #pragma unroll
                for (int reg = 0; reg < 4; ++reg) {
                    float pr = acc[reg] + pbq[du][reg];
                    float cd = pr - cR[du][reg];
                    cdq += cd * cd;
                    cR[du][reg] = pr;
                    unsigned short h = bf16_rne(pr);
                    hi4[reg] = h;
                    lo4[reg] = bf16_rne(pr - bf16_f32(h));
                }
                int off = (kt*16 + q*4)*2;
                *(ushort4v*)(sm + LDS_PR + ((0*6+dof)*16 + b)*144 + off) = hi4;
                *(ushort4v*)(sm + LDS_PR + ((1*6+dof)*16 + b)*144 + off) = lo4;
            }
            cdq += __shfl_xor(cdq, 16, 64);
            cdq += __shfl_xor(cdq, 32, 64);
            if (lane < 16) atomicAdd(&waccF[9*16 + b], cdq);
        }
        __syncthreads();

        // ---- reset own h-sum slots (same-thread, program order suffices) ----
        #pragma unroll
        for (int i = 0; i < 12; ++i) hSL[hbase + i] = 0.f;

        // ---- phases C/D (dynamic m loop — keep dynamic) ----
        for (int m = 0; m < 3; ++m) {
            const float bm = (m==0) ? 0.8f : ((m==1) ? 1.8f : PI_F);
            short8 aMh[2], aMl[2];
            #pragma unroll
            for (int ks = 0; ks < 2; ++ks) {
                aMh[ks] = *(const short8*)(MA + ((((m*8+rt)*2+ks)*2+0)*512 + lane*8));
                aMl[ks] = *(const short8*)(MA + ((((m*8+rt)*2+ks)*2+1)*512 + lane*8));
            }
            float resq = 0.f, sdq = 0.f;
            #pragma unroll
            for (int dof = 0; dof < 6; ++dof) {
                f32x4 acc = {0.f,0.f,0.f,0.f};
                #pragma unroll
                for (int ks = 0; ks < 2; ++ks) {
                    short8 Bh = *(const short8*)(sm + LDS_PR + ((0*6+dof)*16 + b)*144 + (ks*32 + q*8)*2);
                    short8 Bl = *(const short8*)(sm + LDS_PR + ((1*6+dof)*16 + b)*144 + (ks*32 + q*8)*2);
                    acc = mfma16(aMh[ks], Bh, acc);
                    acc = mfma16(aMh[ks], Bl, acc);
                    acc = mfma16(aMl[ks], Bh, acc);
                }
                ushort4v dh, dl, wh, wl;
                unsigned short axh[4];
                unsigned p0 = axp[m][dof][0], p1 = axp[m][dof][1];
                #pragma unroll
                for (int reg = 0; reg < 4; ++reg) {
                    float axn = acc[reg];
                    float axo = bf16_f32((unsigned short)((reg < 2 ? p0 >> (16*reg) : p1 >> (16*(reg-2))) & 0xFFFF));
                    float cl = fminf(bm, fmaxf(-bm, axn));
                    float d  = axn - cl;
                    float wv = axn + cl;
                    resq += d * d;
                    float d1 = fmaxf(0.f, bm - axn) - fmaxf(0.f, bm - axo);
                    float d2 = fmaxf(0.f, bm + axn) - fmaxf(0.f, bm + axo);
                    sdq += d1*d1 + d2*d2;
                    unsigned short h = bf16_rne(d);
                    dh[reg] = h; dl[reg] = bf16_rne(d - bf16_f32(h));
                    h = bf16_rne(wv);
                    wh[reg] = h; wl[reg] = bf16_rne(wv - bf16_f32(h));
                    axh[reg] = bf16_rne(axn);
                }
                int off = (rt*16 + q*4)*2;
                *(ushort4v*)(sm + LDS_D0 + ((0*6+dof)*16 + b)*272 + off) = dh;
                *(ushort4v*)(sm + LDS_D0 + ((1*6+dof)*16 + b)*272 + off) = dl;
                *(ushort4v*)(sm + LDS_W0 + ((0*6+dof)*16 + b)*272 + off) = wh;
                *(ushort4v*)(sm + LDS_W0 + ((1*6+dof)*16 + b)*272 + off) = wl;
                axp[m][dof][0] = ((unsigned)axh[1] << 16) | axh[0];
                axp[m][dof][1] = ((unsigned)axh[3] << 16) | axh[2];
            }
            resq += __shfl_xor(resq, 16, 64); resq += __shfl_xor(resq, 32, 64);
            sdq  += __shfl_xor(sdq, 16, 64);  sdq  += __shfl_xor(sdq, 32, 64);
            if (lane < 16) {
                atomicAdd(&waccF[m*16 + b], resq);
                atomicAdd(&waccF[(3+m)*16 + b], sdq);
            }
            __syncthreads();

            short8 aTh[4], aTl[4];
            #pragma unroll
            for (int ks = 0; ks < 4; ++ks) {
                aTh[ks] = *(const short8*)(MTA + (((((m*4+kt)*4+ks)*2+0)*512) + lane*8));
                aTl[ks] = *(const short8*)(MTA + (((((m*4+kt)*4+ks)*2+1)*512) + lane*8));
            }
            float ldq = 0.f;
            #pragma unroll
            for (int du = 0; du < 3; ++du) {
                int dof = du*2 + dhi;
                f32x4 accD = {0.f,0.f,0.f,0.f};
                f32x4 accH = {0.f,0.f,0.f,0.f};
                #pragma unroll
                for (int ks = 0; ks < 4; ++ks) {
                    short8 Bdh = *(const short8*)(sm + LDS_D0 + ((0*6+dof)*16 + b)*272 + (ks*32 + q*8)*2);
                    short8 Bdl = *(const short8*)(sm + LDS_D0 + ((1*6+dof)*16 + b)*272 + (ks*32 + q*8)*2);
                    short8 Bwh = *(const short8*)(sm + LDS_W0 + ((0*6+dof)*16 + b)*272 + (ks*32 + q*8)*2);
                    short8 Bwl = *(const short8*)(sm + LDS_W0 + ((1*6+dof)*16 + b)*272 + (ks*32 + q*8)*2);
                    accD = mfma16(aTh[ks], Bdh, accD);
                    accD = mfma16(aTh[ks], Bdl, accD);
                    accD = mfma16(aTl[ks], Bdh, accD);
                    accH = mfma16(aTh[ks], Bwh, accH);
                    accH = mfma16(aTh[ks], Bwl, accH);
                    accH = mfma16(aTl[ks], Bwh, accH);
                }
                #pragma unroll
                for (int reg = 0; reg < 4; ++reg) {
                    float delta = accD[reg];
                    float ln2 = lR[m][du][reg] - delta;
                    lR[m][du][reg] = ln2;
                    ldq += delta * delta;
                    hSL[hbase + du*4 + reg] += accH[reg];
                }
            }
            ldq += __shfl_xor(ldq, 16, 64); ldq += __shfl_xor(ldq, 32, 64);
            if (lane < 16) atomicAdd(&waccF[(6+m)*16 + b], ldq);
            __syncthreads();
        }

        if (t < 16) {
            float rp = sqrtf(waccF[0*16+t]) + sqrtf(waccF[1*16+t]) + sqrtf(waccF[2*16+t]);
            float fp = sqrtf(waccF[3*16+t]) + sqrtf(waccF[4*16+t]) + sqrtf(waccF[5*16+t])
                     + sqrtf(waccF[6*16+t]) + sqrtf(waccF[7*16+t]) + sqrtf(waccF[8*16+t])
                     + sqrtf(waccF[9*16+t]);
            accN[t]      += fp;
            accN[16 + t] += rp;
            #pragma unroll
            for (int n = 0; n < 10; ++n) waccF[n*16+t] = 0.f;
        }
        __syncthreads();
    }

    #pragma unroll
    for (int du = 0; du < 3; ++du) {
        int dof = du*2 + dhi;
        #pragma unroll
        for (int reg = 0; reg < 4; ++reg) {
            int k = kt*16 + q*4 + reg;
            outG[(size_t)(bbase+b)*384 + dof*64 + k] = cR[du][reg];
        }
    }
    if (t < 16) {
        outG[(size_t)NBATCH*384 + bbase + t]          = accN[t] / 15.f;
        outG[(size_t)NBATCH*384 + NBATCH + bbase + t] = accN[16 + t] / 15.f;
    }
}

extern "C" void kernel_launch(void* const* d_in, const int* in_sizes, int n_in,
                              void* d_out, int out_size, void* d_ws, size_t ws_size,
                              hipStream_t stream) {
    const float* P     = (const float*)d_in[0];
    const float* Pdot  = (const float*)d_in[1];
    const float* Pddot = (const float*)d_in[2];
    const float* lam   = (const float*)d_in[3];
    const float* csamp = (const float*)d_in[4];
    const float* beq   = (const float*)d_in[5];
    float* out = (float*)d_out;

    float* QdG  = (float*)d_ws;            // 4416 floats; overwritten by Winv
    float* WinvG = (float*)d_ws;           // 69*64 floats (same slot)
    unsigned short* MA  = (unsigned short*)((char*)d_ws + WS_FRAG_OFF);
    unsigned short* MTA = MA + 49152;
    unsigned short* WVA = MTA + 49152;

    hipLaunchKernelGGL(build_qd, dim3(18), dim3(256), 0, stream, P, Pdot, Pddot, QdG);
    hipLaunchKernelGGL(invert_qd, dim3(1), dim3(256), 0, stream, QdG, WinvG);
    hipLaunchKernelGGL(pack_frags, dim3(416), dim3(256), 0, stream, P, Pdot, Pddot, WinvG, MA, MTA, WVA);

    hipFuncSetAttribute((const void*)admm_kernel,
                        hipFuncAttributeMaxDynamicSharedMemorySize, LDS_TOTAL);
    hipLaunchKernelGGL(admm_kernel, dim3(NBATCH/NBPB), dim3(TPB), LDS_TOTAL, stream,
                       lam, csamp, beq, WinvG, MA, MTA, WVA, out);
}

// Round 13
// 463.940 us; speedup vs baseline: 10.0563x; 1.1873x over previous
//
#include <hip/hip_runtime.h>
#include <math.h>

#define NITER 15
#define TPB 512
#define NBATCH 4096
#define NBPB 16
#define PI_F 3.14159265358979323846f

typedef __attribute__((ext_vector_type(8))) short short8;
typedef __attribute__((ext_vector_type(4))) float f32x4;
typedef __attribute__((ext_vector_type(4))) unsigned short ushort4v;

// ---------------- LDS layout (bytes) ----------------
// region1: D0 single-plane d [dof6][b16][136 bf16] = 26112, aliases LN 2-plane (27648)
// PR 2-plane 27648 ; W0 2-plane 52224 ; wacc 640 ; accN 128
// slot region: [512 threads][25 floats] — L at +0..11, hS at +12..23, 1 pad
//   (25 coprime 32 -> 2 lanes/bank = conflict-free)
#define LDS_D0   0
#define LDS_LN   0
#define LDS_PR   27648
#define LDS_W0   55296
#define LDS_WACC 107520
#define LDS_ACCN 108160
#define LDS_SLOT 108288
#define SLOT_STRIDE 25
#define LDS_TOTAL (108288 + 512*SLOT_STRIDE*4)   // 159488 <= 163840

// ---------------- ws layout ----------------
// [0, 17664): QdG (4416 floats) -> overwritten by Winv[69][64]
#define WS_FRAG_OFF 17920

__device__ __forceinline__ unsigned short bf16_rne(float x) {
    unsigned u = __float_as_uint(x);
    unsigned r = (u + 0x7FFFu + ((u >> 16) & 1u)) >> 16;
    return (unsigned short)r;
}
__device__ __forceinline__ float bf16_f32(unsigned short h) {
    return __uint_as_float(((unsigned)h) << 16);
}

// ===================== K0: build Qd entries (fully parallel) =====================
__global__ void build_qd(const float* __restrict__ P, const float* __restrict__ Pd,
                         const float* __restrict__ Pdd, float* __restrict__ QdG) {
    int idx = blockIdx.x*256 + threadIdx.x;
    if (idx < 4096) {
        int i = idx >> 6, j = idx & 63;
        float acc = 0.f;
        for (int r = 0; r < 128; ++r) {
            acc += Pd[r*64+i]*Pd[r*64+j];
            acc += Pdd[r*64+i]*Pdd[r*64+j];
            acc += P[r*64+i]*P[r*64+j];
        }
        QdG[idx] = (i == j ? 1.f : 0.f) + 2.f*acc;
    } else if (idx < 4416) {
        int r2 = idx - 4096;
        int e = r2 >> 6, k = r2 & 63;
        float v = (e == 0) ? P[k] : (e == 1) ? Pd[k] : (e == 2) ? Pdd[k]
                : (e == 3) ? Pd[127*64+k] : Pdd[127*64+k];
        QdG[idx] = v;
    }
}

// ===================== K1: invert Qd — parallel argmax + fused swap (green) =====
__global__ void invert_qd(const float* __restrict__ QdG, float* __restrict__ Winv) {
    __shared__ float aug[69][140];
    __shared__ float prow[140];
    __shared__ float srow[140];
    __shared__ int   pivS;
    __shared__ float invS;
    const int t = threadIdx.x;  // 256

    for (int idx = t; idx < 69*140; idx += 256) aug[idx/140][idx%140] = 0.f;
    __syncthreads();
    for (int idx = t; idx < 4096; idx += 256) aug[idx >> 6][idx & 63] = QdG[idx];
    for (int idx = t; idx < 320; idx += 256) {
        int e = idx >> 6, k = idx & 63;
        float v = QdG[4096 + idx];
        aug[k][64+e] = v;
        aug[64+e][k] = v;
    }
    for (int i = t; i < 69; i += 256) aug[i][69+i] = 1.f;
    __syncthreads();

    const int gr = t >> 1;
    const int gh = t & 1;
    for (int p = 0; p < 69; ++p) {
        if (t < 64) {
            float bv = -1.f; int bi = p;
            for (int r = p + t; r < 69; r += 64) {
                float a = fabsf(aug[r][p]);
                if (a > bv) { bv = a; bi = r; }
            }
            #pragma unroll
            for (int off = 32; off > 0; off >>= 1) {
                float ov = __shfl_xor(bv, off, 64);
                int   oi = __shfl_xor(bi, off, 64);
                if (ov > bv || (ov == bv && oi < bi)) { bv = ov; bi = oi; }
            }
            if (t == 0) { pivS = bi; invS = 1.f / aug[bi][p]; }
        }
        __syncthreads();
        const int pv = pivS;
        const float inv = invS;
        float fi = 0.f;
        if (gr < 69) fi = aug[gr][p];
        if (t < 140) {
            prow[t] = aug[pv][t] * inv;
            srow[t] = aug[p][t];
        }
        __syncthreads();
        if (gr < 69) {
            const int cb = gh * 70;
            if (gr == p) {
                #pragma unroll 7
                for (int j = 0; j < 70; ++j) aug[p][cb+j] = prow[cb+j];
            } else if (gr == pv) {
                const float f2 = srow[p];
                #pragma unroll 7
                for (int j = 0; j < 70; ++j) aug[pv][cb+j] = srow[cb+j] - f2 * prow[cb+j];
            } else {
                #pragma unroll 7
                for (int j = 0; j < 70; ++j) aug[gr][cb+j] -= fi * prow[cb+j];
            }
        }
        __syncthreads();
    }
    for (int idx = t; idx < 69*64; idx += 256) Winv[idx] = aug[idx >> 6][69 + (idx & 63)];
}

// ===================== K2: pack bf16 hi/lo MFMA A-fragments =====================
__global__ void pack_frags(const float* __restrict__ P, const float* __restrict__ Pd,
                           const float* __restrict__ Pdd, const float* __restrict__ WinvG,
                           unsigned short* __restrict__ MA, unsigned short* __restrict__ MTA,
                           unsigned short* __restrict__ WVA) {
    int tid = blockIdx.x*256 + threadIdx.x;
    if (tid < 49152) {                       // MA [m][rt8][ks2][pl2][lane][8] ; A = M[r][k]
        int j = tid & 7, lane = (tid>>3)&63, pl = (tid>>9)&1, ks = (tid>>10)&1, rt = (tid>>11)&7, m = tid>>14;
        const float* src = (m==0) ? Pd : ((m==1) ? Pdd : P);
        int r = rt*16 + (lane&15);
        int k = ks*32 + (lane>>4)*8 + j;
        float x = src[r*64+k];
        unsigned short hi = bf16_rne(x);
        MA[tid] = pl ? bf16_rne(x - bf16_f32(hi)) : hi;
    } else if (tid < 98304) {                // MTA [m][kt4][ks4][pl2][lane][8] ; A = M^T[k][r]
        int t2 = tid - 49152;
        int j = t2 & 7, lane = (t2>>3)&63, pl = (t2>>9)&1, ks = (t2>>10)&3, kt = (t2>>12)&3, m = t2>>14;
        const float* src = (m==0) ? Pd : ((m==1) ? Pdd : P);
        int k = kt*16 + (lane&15);
        int r = ks*32 + (lane>>4)*8 + j;
        float x = src[r*64+k];
        unsigned short hi = bf16_rne(x);
        MTA[t2] = pl ? bf16_rne(x - bf16_f32(hi)) : hi;
    } else if (tid < 106496) {               // WVA [kt4][js2][pl2][lane][8] ; A = Winv[k'][jj]
        int t3 = tid - 98304;
        int j = t3 & 7, lane = (t3>>3)&63, pl = (t3>>9)&1, js = (t3>>10)&1, kt = t3>>11;
        int kp = kt*16 + (lane&15);
        int jj = js*32 + (lane>>4)*8 + j;
        float x = WinvG[jj*64 + kp];
        unsigned short hi = bf16_rne(x);
        WVA[t3] = pl ? bf16_rne(x - bf16_f32(hi)) : hi;
    }
}

// ===================== main ADMM kernel =====================
__device__ __forceinline__ f32x4 mfma16(short8 a, short8 b, f32x4 c) {
    return __builtin_amdgcn_mfma_f32_16x16x32_bf16(a, b, c, 0, 0, 0);
}

// State residency rule (R4-R11): persistent accumulators must NOT be register-
// promoted (miscompiles). L (=sum_m lambda) and hS (=sum_m h_m) live in
// per-thread LDS slots; only axp (prev-ax bf16) remains in scratch (144 B/thread
// -> 2.4 MB/XCD, L2-resident).
__global__ void __launch_bounds__(TPB, 2)
admm_kernel(const float* __restrict__ lamG, const float* __restrict__ cG,
            const float* __restrict__ beqG, const float* __restrict__ WinvG,
            const unsigned short* __restrict__ MA, const unsigned short* __restrict__ MTA,
            const unsigned short* __restrict__ WVA, float* __restrict__ outG) {
    extern __shared__ char sm[];
    float* waccF = (float*)(sm + LDS_WACC);   // [10][16]
    float* accN  = (float*)(sm + LDS_ACCN);   // [2][16]
    float* slotF = (float*)(sm + LDS_SLOT);   // [512][25]: L +0..11, hS +12..23

    const int t = threadIdx.x;
    const int lane = t & 63;
    const int w = t >> 6;
    const int b = lane & 15;
    const int q = lane >> 4;
    const int kt = w & 3;
    const int dhi = w >> 2;
    const int rt = w;
    const int bbase = blockIdx.x * NBPB;
    const int sb = t * SLOT_STRIDE;

    float cR[3][4];
    float pbq[3][4];
    unsigned axp[3][6][2];   // prev ax, bf16-packed; dynamic m -> scratch (L2-resident)

    for (int i = t; i < 160 + 32; i += TPB) ((float*)(sm + LDS_WACC))[i] = 0.f;
    #pragma unroll
    for (int i = 0; i < 12; ++i) slotF[sb + 12 + i] = 0.f;   // hS = 0

    #pragma unroll
    for (int du = 0; du < 3; ++du) {
        int dof = du*2 + dhi;
        #pragma unroll
        for (int reg = 0; reg < 4; ++reg) {
            int k = kt*16 + q*4 + reg;
            cR[du][reg] = cG[(size_t)(bbase+b)*384 + dof*64 + k];
            float ls = 0.f;
            #pragma unroll
            for (int m = 0; m < 3; ++m)
                ls += lamG[(size_t)(bbase+b)*1152 + m*384 + dof*64 + k];
            slotF[sb + du*4 + reg] = ls;                      // L init
            float s = 0.f;
            #pragma unroll
            for (int e = 0; e < 5; ++e)
                s += WinvG[(64+e)*64 + k] * beqG[(size_t)(bbase+b)*30 + dof*5 + e];
            pbq[du][reg] = s;
        }
    }

    #pragma unroll
    for (int du = 0; du < 3; ++du) {
        int dof = du*2 + dhi;
        ushort4v hi4, lo4;
        #pragma unroll
        for (int reg = 0; reg < 4; ++reg) {
            unsigned short h = bf16_rne(cR[du][reg]);
            hi4[reg] = h;
            lo4[reg] = bf16_rne(cR[du][reg] - bf16_f32(h));
        }
        int off = (kt*16 + q*4)*2;
        *(ushort4v*)(sm + LDS_PR + ((0*6+dof)*16 + b)*144 + off) = hi4;
        *(ushort4v*)(sm + LDS_PR + ((1*6+dof)*16 + b)*144 + off) = lo4;
    }
    __syncthreads();

    // ---- prologue (dynamic m loop — keep dynamic; register-promoted state miscompiles) ----
    for (int m = 0; m < 3; ++m) {
        const float bm = (m==0) ? 0.8f : ((m==1) ? 1.8f : PI_F);
        short8 aMh[2], aMl[2];
        #pragma unroll
        for (int ks = 0; ks < 2; ++ks) {
            aMh[ks] = *(const short8*)(MA + ((((m*8+rt)*2+ks)*2+0)*512 + lane*8));
            aMl[ks] = *(const short8*)(MA + ((((m*8+rt)*2+ks)*2+1)*512 + lane*8));
        }
        #pragma unroll
        for (int dof = 0; dof < 6; ++dof) {
            f32x4 acc = {0.f,0.f,0.f,0.f};
            #pragma unroll
            for (int ks = 0; ks < 2; ++ks) {
                short8 Bh = *(const short8*)(sm + LDS_PR + ((0*6+dof)*16 + b)*144 + (ks*32 + q*8)*2);
                short8 Bl = *(const short8*)(sm + LDS_PR + ((1*6+dof)*16 + b)*144 + (ks*32 + q*8)*2);
                acc = mfma16(aMh[ks], Bh, acc);
                acc = mfma16(aMh[ks], Bl, acc);
                acc = mfma16(aMl[ks], Bh, acc);
            }
            ushort4v wh, wl;
            unsigned short axh[4];
            #pragma unroll
            for (int reg = 0; reg < 4; ++reg) {
                float axn = acc[reg];
                float cl = fminf(bm, fmaxf(-bm, axn));
                float wv = axn + cl;
                unsigned short h = bf16_rne(wv);
                wh[reg] = h;
                wl[reg] = bf16_rne(wv - bf16_f32(h));
                axh[reg] = bf16_rne(axn);
            }
            int off = (rt*16 + q*4)*2;
            *(ushort4v*)(sm + LDS_W0 + ((0*6+dof)*16 + b)*272 + off) = wh;
            *(ushort4v*)(sm + LDS_W0 + ((1*6+dof)*16 + b)*272 + off) = wl;
            axp[m][dof][0] = ((unsigned)axh[1] << 16) | axh[0];
            axp[m][dof][1] = ((unsigned)axh[3] << 16) | axh[2];
        }
        __syncthreads();
        short8 aTh[4], aTl[4];
        #pragma unroll
        for (int ks = 0; ks < 4; ++ks) {
            aTh[ks] = *(const short8*)(MTA + (((((m*4+kt)*4+ks)*2+0)*512) + lane*8));
            aTl[ks] = *(const short8*)(MTA + (((((m*4+kt)*4+ks)*2+1)*512) + lane*8));
        }
        #pragma unroll
        for (int du = 0; du < 3; ++du) {
            int dof = du*2 + dhi;
            f32x4 accH = {0.f,0.f,0.f,0.f};
            #pragma unroll
            for (int ks = 0; ks < 4; ++ks) {
                short8 Bwh = *(const short8*)(sm + LDS_W0 + ((0*6+dof)*16 + b)*272 + (ks*32 + q*8)*2);
                short8 Bwl = *(const short8*)(sm + LDS_W0 + ((1*6+dof)*16 + b)*272 + (ks*32 + q*8)*2);
                accH = mfma16(aTh[ks], Bwh, accH);
                accH = mfma16(aTh[ks], Bwl, accH);
                accH = mfma16(aTl[ks], Bwh, accH);
            }
            #pragma unroll
            for (int reg = 0; reg < 4; ++reg)
                slotF[sb + 12 + du*4 + reg] += accH[reg];
        }
        __syncthreads();
    }

    // ==================== 15 iterations ====================
    for (int it = 0; it < NITER; ++it) {
        // ---- phase A: t = L + hS + c ----
        #pragma unroll
        for (int du = 0; du < 3; ++du) {
            int dof = du*2 + dhi;
            ushort4v hi4, lo4;
            #pragma unroll
            for (int reg = 0; reg < 4; ++reg) {
                float tv = slotF[sb + du*4 + reg] + slotF[sb + 12 + du*4 + reg] + cR[du][reg];
                unsigned short h = bf16_rne(tv);
                hi4[reg] = h;
                lo4[reg] = bf16_rne(tv - bf16_f32(h));
            }
            int off = (kt*16 + q*4)*2;
            *(ushort4v*)(sm + LDS_LN + ((0*6+dof)*16 + b)*144 + off) = hi4;
            *(ushort4v*)(sm + LDS_LN + ((1*6+dof)*16 + b)*144 + off) = lo4;
        }
        __syncthreads();

        // ---- phase B: primal ----
        {
            short8 aWh[2], aWl[2];
            #pragma unroll
            for (int js = 0; js < 2; ++js) {
                aWh[js] = *(const short8*)(WVA + (((kt*2+js)*2+0)*512 + lane*8));
                aWl[js] = *(const short8*)(WVA + (((kt*2+js)*2+1)*512 + lane*8));
            }
            float cdq = 0.f;
            #pragma unroll
            for (int du = 0; du < 3; ++du) {
                int dof = du*2 + dhi;
                f32x4 acc = {0.f,0.f,0.f,0.f};
                #pragma unroll
                for (int js = 0; js < 2; ++js) {
                    short8 Bh = *(const short8*)(sm + LDS_LN + ((0*6+dof)*16 + b)*144 + (js*32 + q*8)*2);
                    short8 Bl = *(const short8*)(sm + LDS_LN + ((1*6+dof)*16 + b)*144 + (js*32 + q*8)*2);
                    acc = mfma16(aWh[js], Bh, acc);
                    acc = mfma16(aWh[js], Bl, acc);
                    acc = mfma16(aWl[js], Bh, acc);
                }
                ushort4v hi4, lo4;
                #pragma unroll
                for (int reg = 0; reg < 4; ++reg) {
                    float pr = acc[reg] + pbq[du][reg];
                    float cd = pr - cR[du][reg];
                    cdq += cd * cd;
                    cR[du][reg] = pr;
                    unsigned short h = bf16_rne(pr);
                    hi4[reg] = h;
                    lo4[reg] = bf16_rne(pr - bf16_f32(h));
                }
                int off = (kt*16 + q*4)*2;
                *(ushort4v*)(sm + LDS_PR + ((0*6+dof)*16 + b)*144 + off) = hi4;
                *(ushort4v*)(sm + LDS_PR + ((1*6+dof)*16 + b)*144 + off) = lo4;
            }
            cdq += __shfl_xor(cdq, 16, 64);
            cdq += __shfl_xor(cdq, 32, 64);
            if (lane < 16) atomicAdd(&waccF[9*16 + b], cdq);
        }
        __syncthreads();

        // ---- reset own hS slots (same-thread, program order suffices) ----
        #pragma unroll
        for (int i = 0; i < 12; ++i) slotF[sb + 12 + i] = 0.f;

        // ---- phases C/D (dynamic m loop — keep dynamic) ----
        for (int m = 0; m < 3; ++m) {
            const float bm = (m==0) ? 0.8f : ((m==1) ? 1.8f : PI_F);
            short8 aMh[2], aMl[2];
            #pragma unroll
            for (int ks = 0; ks < 2; ++ks) {
                aMh[ks] = *(const short8*)(MA + ((((m*8+rt)*2+ks)*2+0)*512 + lane*8));
                aMl[ks] = *(const short8*)(MA + ((((m*8+rt)*2+ks)*2+1)*512 + lane*8));
            }
            float resq = 0.f, sdq = 0.f;
            #pragma unroll
            for (int dof = 0; dof < 6; ++dof) {
                f32x4 acc = {0.f,0.f,0.f,0.f};
                #pragma unroll
                for (int ks = 0; ks < 2; ++ks) {
                    short8 Bh = *(const short8*)(sm + LDS_PR + ((0*6+dof)*16 + b)*144 + (ks*32 + q*8)*2);
                    short8 Bl = *(const short8*)(sm + LDS_PR + ((1*6+dof)*16 + b)*144 + (ks*32 + q*8)*2);
                    acc = mfma16(aMh[ks], Bh, acc);
                    acc = mfma16(aMh[ks], Bl, acc);
                    acc = mfma16(aMl[ks], Bh, acc);
                }
                ushort4v dh, wh, wl;
                unsigned short axh[4];
                unsigned p0 = axp[m][dof][0], p1 = axp[m][dof][1];
                #pragma unroll
                for (int reg = 0; reg < 4; ++reg) {
                    float axn = acc[reg];
                    float axo = bf16_f32((unsigned short)((reg < 2 ? p0 >> (16*reg) : p1 >> (16*(reg-2))) & 0xFFFF));
                    float cl = fminf(bm, fmaxf(-bm, axn));
                    float d  = axn - cl;
                    float wv = axn + cl;
                    resq += d * d;
                    float d1 = fmaxf(0.f, bm - axn) - fmaxf(0.f, bm - axo);
                    float d2 = fmaxf(0.f, bm + axn) - fmaxf(0.f, bm + axo);
                    sdq += d1*d1 + d2*d2;
                    dh[reg] = bf16_rne(d);
                    unsigned short h = bf16_rne(wv);
                    wh[reg] = h;
                    wl[reg] = bf16_rne(wv - bf16_f32(h));
                    axh[reg] = bf16_rne(axn);
                }
                int off = (rt*16 + q*4)*2;
                *(ushort4v*)(sm + LDS_D0 + (dof*16 + b)*272 + off) = dh;
                *(ushort4v*)(sm + LDS_W0 + ((0*6+dof)*16 + b)*272 + off) = wh;
                *(ushort4v*)(sm + LDS_W0 + ((1*6+dof)*16 + b)*272 + off) = wl;
                axp[m][dof][0] = ((unsigned)axh[1] << 16) | axh[0];
                axp[m][dof][1] = ((unsigned)axh[3] << 16) | axh[2];
            }
            resq += __shfl_xor(resq, 16, 64); resq += __shfl_xor(resq, 32, 64);
            sdq  += __shfl_xor(sdq, 16, 64);  sdq  += __shfl_xor(sdq, 32, 64);
            if (lane < 16) {
                atomicAdd(&waccF[m*16 + b], resq);
                atomicAdd(&waccF[(3+m)*16 + b], sdq);
            }
            __syncthreads();

            short8 aTh[4], aTl[4];
            #pragma unroll
            for (int ks = 0; ks < 4; ++ks) {
                aTh[ks] = *(const short8*)(MTA + (((((m*4+kt)*4+ks)*2+0)*512) + lane*8));
                aTl[ks] = *(const short8*)(MTA + (((((m*4+kt)*4+ks)*2+1)*512) + lane*8));
            }
            float ldq = 0.f;
            #pragma unroll
            for (int du = 0; du < 3; ++du) {
                int dof = du*2 + dhi;
                f32x4 accD = {0.f,0.f,0.f,0.f};
                f32x4 accH = {0.f,0.f,0.f,0.f};
                #pragma unroll
                for (int ks = 0; ks < 4; ++ks) {
                    short8 Bdh = *(const short8*)(sm + LDS_D0 + (dof*16 + b)*272 + (ks*32 + q*8)*2);
                    short8 Bwh = *(const short8*)(sm + LDS_W0 + ((0*6+dof)*16 + b)*272 + (ks*32 + q*8)*2);
                    short8 Bwl = *(const short8*)(sm + LDS_W0 + ((1*6+dof)*16 + b)*272 + (ks*32 + q*8)*2);
                    accD = mfma16(aTh[ks], Bdh, accD);
                    accD = mfma16(aTl[ks], Bdh, accD);
                    accH = mfma16(aTh[ks], Bwh, accH);
                    accH = mfma16(aTh[ks], Bwl, accH);
                    accH = mfma16(aTl[ks], Bwh, accH);
                }
                #pragma unroll
                for (int reg = 0; reg < 4; ++reg) {
                    float delta = accD[reg];
                    slotF[sb + du*4 + reg] -= delta;           // L update (own LDS slot)
                    ldq += delta * delta;
                    slotF[sb + 12 + du*4 + reg] += accH[reg];  // hS accumulate
                }
            }
            ldq += __shfl_xor(ldq, 16, 64); ldq += __shfl_xor(ldq, 32, 64);
            if (lane < 16) atomicAdd(&waccF[(6+m)*16 + b], ldq);
            __syncthreads();
        }

        if (t < 16) {
            float rp = sqrtf(waccF[0*16+t]) + sqrtf(waccF[1*16+t]) + sqrtf(waccF[2*16+t]);
            float fp = sqrtf(waccF[3*16+t]) + sqrtf(waccF[4*16+t]) + sqrtf(waccF[5*16+t])
                     + sqrtf(waccF[6*16+t]) + sqrtf(waccF[7*16+t]) + sqrtf(waccF[8*16+t])
                     + sqrtf(waccF[9*16+t]);
            accN[t]      += fp;
            accN[16 + t] += rp;
            #pragma unroll
            for (int n = 0; n < 10; ++n) waccF[n*16+t] = 0.f;
        }
        __syncthreads();
    }

    #pragma unroll
    for (int du = 0; du < 3; ++du) {
        int dof = du*2 + dhi;
        #pragma unroll
        for (int reg = 0; reg < 4; ++reg) {
            int k = kt*16 + q*4 + reg;
            outG[(size_t)(bbase+b)*384 + dof*64 + k] = cR[du][reg];
        }
    }
    if (t < 16) {
        outG[(size_t)NBATCH*384 + bbase + t]          = accN[t] / 15.f;
        outG[(size_t)NBATCH*384 + NBATCH + bbase + t] = accN[16 + t] / 15.f;
    }
}

extern "C" void kernel_launch(void* const* d_in, const int* in_sizes, int n_in,
                              void* d_out, int out_size, void* d_ws, size_t ws_size,
                              hipStream_t stream) {
    const float* P     = (const float*)d_in[0];
    const float* Pdot  = (const float*)d_in[1];
    const float* Pddot = (const float*)d_in[2];
    const float* lam   = (const float*)d_in[3];
    const float* csamp = (const float*)d_in[4];
    const float* beq   = (const float*)d_in[5];
    float* out = (float*)d_out;

    float* QdG  = (float*)d_ws;            // 4416 floats; overwritten by Winv
    float* WinvG = (float*)d_ws;           // 69*64 floats (same slot)
    unsigned short* MA  = (unsigned short*)((char*)d_ws + WS_FRAG_OFF);
    unsigned short* MTA = MA + 49152;
    unsigned short* WVA = MTA + 49152;

    hipLaunchKernelGGL(build_qd, dim3(18), dim3(256), 0, stream, P, Pdot, Pddot, QdG);
    hipLaunchKernelGGL(invert_qd, dim3(1), dim3(256), 0, stream, QdG, WinvG);
    hipLaunchKernelGGL(pack_frags, dim3(416), dim3(256), 0, stream, P, Pdot, Pddot, WinvG, MA, MTA, WVA);

    hipFuncSetAttribute((const void*)admm_kernel,
                        hipFuncAttributeMaxDynamicSharedMemorySize, LDS_TOTAL);
    hipLaunchKernelGGL(admm_kernel, dim3(NBATCH/NBPB), dim3(TPB), LDS_TOTAL, stream,
                       lam, csamp, beq, WinvG, MA, MTA, WVA, out);
}

// Round 15
// 452.469 us; speedup vs baseline: 10.3113x; 1.0254x over previous
//
#include <hip/hip_runtime.h>
#include <math.h>

#define NITER 15
#define TPB 512
#define NBATCH 4096
#define NBPB 16
#define PI_F 3.14159265358979323846f

typedef __attribute__((ext_vector_type(8))) short short8;
typedef __attribute__((ext_vector_type(4))) float f32x4;
typedef __attribute__((ext_vector_type(4))) unsigned short ushort4v;

// ---------------- LDS layout (bytes) ----------------
#define LDS_D0   0
#define LDS_LN   0
#define LDS_PR   27648
#define LDS_W0   55296
#define LDS_WACC 107520
#define LDS_ACCN 108160
#define LDS_SLOT 108288
#define SLOT_STRIDE 25
#define LDS_TOTAL (108288 + 512*SLOT_STRIDE*4)   // 159488 <= 163840

// ---------------- ws layout ----------------
#define WS_FRAG_OFF 17920

__device__ __forceinline__ unsigned short bf16_rne(float x) {
    unsigned u = __float_as_uint(x);
    unsigned r = (u + 0x7FFFu + ((u >> 16) & 1u)) >> 16;
    return (unsigned short)r;
}
__device__ __forceinline__ float bf16_f32(unsigned short h) {
    return __uint_as_float(((unsigned)h) << 16);
}

// ===================== K1: pack MA/MTA (blocks 0..383) + build Qd (blocks 384..401) ==
__global__ void pack_and_build(const float* __restrict__ P, const float* __restrict__ Pd,
                               const float* __restrict__ Pdd, float* __restrict__ QdG,
                               unsigned short* __restrict__ MA, unsigned short* __restrict__ MTA) {
    if (blockIdx.x < 384) {
        int tid = blockIdx.x*256 + threadIdx.x;
        if (tid < 49152) {                       // MA [m][rt8][ks2][pl2][lane][8] ; A = M[r][k]
            int j = tid & 7, lane = (tid>>3)&63, pl = (tid>>9)&1, ks = (tid>>10)&1, rt = (tid>>11)&7, m = tid>>14;
            const float* src = (m==0) ? Pd : ((m==1) ? Pdd : P);
            int r = rt*16 + (lane&15);
            int k = ks*32 + (lane>>4)*8 + j;
            float x = src[r*64+k];
            unsigned short hi = bf16_rne(x);
            MA[tid] = pl ? bf16_rne(x - bf16_f32(hi)) : hi;
        } else {                                 // MTA [m][kt4][ks4][pl2][lane][8] ; A = M^T[k][r]
            int t2 = tid - 49152;
            int j = t2 & 7, lane = (t2>>3)&63, pl = (t2>>9)&1, ks = (t2>>10)&3, kt = (t2>>12)&3, m = t2>>14;
            const float* src = (m==0) ? Pd : ((m==1) ? Pdd : P);
            int k = kt*16 + (lane&15);
            int r = ks*32 + (lane>>4)*8 + j;
            float x = src[r*64+k];
            unsigned short hi = bf16_rne(x);
            MTA[t2] = pl ? bf16_rne(x - bf16_f32(hi)) : hi;
        }
    } else {
        int idx = (blockIdx.x - 384)*256 + threadIdx.x;
        if (idx < 4096) {
            int i = idx >> 6, j = idx & 63;
            float acc = 0.f;
            for (int r = 0; r < 128; ++r) {
                acc += Pd[r*64+i]*Pd[r*64+j];
                acc += Pdd[r*64+i]*Pdd[r*64+j];
                acc += P[r*64+i]*P[r*64+j];
            }
            QdG[idx] = (i == j ? 1.f : 0.f) + 2.f*acc;
        } else if (idx < 4416) {
            int r2 = idx - 4096;
            int e = r2 >> 6, k = r2 & 63;
            float v = (e == 0) ? P[k] : (e == 1) ? Pd[k] : (e == 2) ? Pdd[k]
                    : (e == 3) ? Pd[127*64+k] : Pdd[127*64+k];
            QdG[idx] = v;
        }
    }
}

// ===================== K2: invert Qd (2 barriers/pivot) + pack WVA + Winv rows 64..68 ==
// Pivot selection identical to R10 (first-max, same butterfly) -> bit-identical Winv.
__global__ void invert_qd(const float* __restrict__ QdG, float* __restrict__ Winv,
                          unsigned short* __restrict__ WVA) {
    __shared__ float aug[69][140];
    __shared__ float prow[140];
    __shared__ float srow[140];
    const int t = threadIdx.x;  // 256
    const int lane = t & 63;

    for (int idx = t; idx < 69*140; idx += 256) aug[idx/140][idx%140] = 0.f;
    __syncthreads();
    for (int idx = t; idx < 4096; idx += 256) aug[idx >> 6][idx & 63] = QdG[idx];
    for (int idx = t; idx < 320; idx += 256) {
        int e = idx >> 6, k = idx & 63;
        float v = QdG[4096 + idx];
        aug[k][64+e] = v;
        aug[64+e][k] = v;
    }
    for (int i = t; i < 69; i += 256) aug[i][69+i] = 1.f;
    __syncthreads();

    const int gr = t >> 1;        // row 0..127
    const int gh = t & 1;         // col half
    for (int p = 0; p < 69; ++p) {
        // redundant per-wave argmax: every lane ends with identical (bv, bi)
        float bv = -1.f; int bi = p;
        for (int r = p + lane; r < 69; r += 64) {
            float a = fabsf(aug[r][p]);
            if (a > bv) { bv = a; bi = r; }
        }
        #pragma unroll
        for (int off = 32; off > 0; off >>= 1) {
            float ov = __shfl_xor(bv, off, 64);
            int   oi = __shfl_xor(bi, off, 64);
            if (ov > bv || (ov == bv && oi < bi)) { bv = ov; bi = oi; }
        }
        const int pv = bi;
        const float inv = 1.f / aug[pv][p];
        float fi = 0.f;
        if (gr < 69) fi = aug[gr][p];
        if (t < 140) {
            prow[t] = aug[pv][t] * inv;
            srow[t] = aug[p][t];
        }
        __syncthreads();          // reads (argmax/fi/snapshot) done before writes
        if (gr < 69) {
            const int cb = gh * 70;
            if (gr == p) {
                #pragma unroll 7
                for (int j = 0; j < 70; ++j) aug[p][cb+j] = prow[cb+j];
            } else if (gr == pv) {
                const float f2 = srow[p];
                #pragma unroll 7
                for (int j = 0; j < 70; ++j) aug[pv][cb+j] = srow[cb+j] - f2 * prow[cb+j];
            } else {
                #pragma unroll 7
                for (int j = 0; j < 70; ++j) aug[gr][cb+j] -= fi * prow[cb+j];
            }
        }
        __syncthreads();          // elimination done before next argmax
    }

    // tail: Winv rows 64..68 (for admm pbq) + WVA fragments straight from LDS
    for (int idx = t; idx < 320; idx += 256)
        Winv[4096 + idx] = aug[64 + (idx >> 6)][69 + (idx & 63)];
    for (int idx = t; idx < 8192; idx += 256) {
        int j = idx & 7, ln = (idx>>3)&63, pl = (idx>>9)&1, js = (idx>>10)&1, kt2 = idx>>11;
        int kp = kt2*16 + (ln&15);
        int jj = js*32 + (ln>>4)*8 + j;
        float x = aug[jj][69 + kp];
        unsigned short hi = bf16_rne(x);
        WVA[idx] = pl ? bf16_rne(x - bf16_f32(hi)) : hi;
    }
}

// ===================== main ADMM kernel — R13 VERBATIM (green, do not perturb) ==
// State residency rule (R4-R14): persistent accumulators must NOT be register-
// promoted; no unrolling of the m loops; no inline asm in this kernel. L and hS
// live in per-thread LDS slots; axp in scratch (L2-resident).
__device__ __forceinline__ f32x4 mfma16(short8 a, short8 b, f32x4 c) {
    return __builtin_amdgcn_mfma_f32_16x16x32_bf16(a, b, c, 0, 0, 0);
}

__global__ void __launch_bounds__(TPB, 2)
admm_kernel(const float* __restrict__ lamG, const float* __restrict__ cG,
            const float* __restrict__ beqG, const float* __restrict__ WinvG,
            const unsigned short* __restrict__ MA, const unsigned short* __restrict__ MTA,
            const unsigned short* __restrict__ WVA, float* __restrict__ outG) {
    extern __shared__ char sm[];
    float* waccF = (float*)(sm + LDS_WACC);   // [10][16]
    float* accN  = (float*)(sm + LDS_ACCN);   // [2][16]
    float* slotF = (float*)(sm + LDS_SLOT);   // [512][25]: L +0..11, hS +12..23

    const int t = threadIdx.x;
    const int lane = t & 63;
    const int w = t >> 6;
    const int b = lane & 15;
    const int q = lane >> 4;
    const int kt = w & 3;
    const int dhi = w >> 2;
    const int rt = w;
    const int bbase = blockIdx.x * NBPB;
    const int sb = t * SLOT_STRIDE;

    float cR[3][4];
    float pbq[3][4];
    unsigned axp[3][6][2];   // prev ax, bf16-packed; dynamic m -> scratch (L2-resident)

    for (int i = t; i < 160 + 32; i += TPB) ((float*)(sm + LDS_WACC))[i] = 0.f;
    #pragma unroll
    for (int i = 0; i < 12; ++i) slotF[sb + 12 + i] = 0.f;   // hS = 0

    #pragma unroll
    for (int du = 0; du < 3; ++du) {
        int dof = du*2 + dhi;
        #pragma unroll
        for (int reg = 0; reg < 4; ++reg) {
            int k = kt*16 + q*4 + reg;
            cR[du][reg] = cG[(size_t)(bbase+b)*384 + dof*64 + k];
            float ls = 0.f;
            #pragma unroll
            for (int m = 0; m < 3; ++m)
                ls += lamG[(size_t)(bbase+b)*1152 + m*384 + dof*64 + k];
            slotF[sb + du*4 + reg] = ls;                      // L init
            float s = 0.f;
            #pragma unroll
            for (int e = 0; e < 5; ++e)
                s += WinvG[(64+e)*64 + k] * beqG[(size_t)(bbase+b)*30 + dof*5 + e];
            pbq[du][reg] = s;
        }
    }

    #pragma unroll
    for (int du = 0; du < 3; ++du) {
        int dof = du*2 + dhi;
        ushort4v hi4, lo4;
        #pragma unroll
        for (int reg = 0; reg < 4; ++reg) {
            unsigned short h = bf16_rne(cR[du][reg]);
            hi4[reg] = h;
            lo4[reg] = bf16_rne(cR[du][reg] - bf16_f32(h));
        }
        int off = (kt*16 + q*4)*2;
        *(ushort4v*)(sm + LDS_PR + ((0*6+dof)*16 + b)*144 + off) = hi4;
        *(ushort4v*)(sm + LDS_PR + ((1*6+dof)*16 + b)*144 + off) = lo4;
    }
    __syncthreads();

    // ---- prologue (dynamic m loop — keep dynamic; register-promoted state miscompiles) ----
    for (int m = 0; m < 3; ++m) {
        const float bm = (m==0) ? 0.8f : ((m==1) ? 1.8f : PI_F);
        short8 aMh[2], aMl[2];
        #pragma unroll
        for (int ks = 0; ks < 2; ++ks) {
            aMh[ks] = *(const short8*)(MA + ((((m*8+rt)*2+ks)*2+0)*512 + lane*8));
            aMl[ks] = *(const short8*)(MA + ((((m*8+rt)*2+ks)*2+1)*512 + lane*8));
        }
        #pragma unroll
        for (int dof = 0; dof < 6; ++dof) {
            f32x4 acc = {0.f,0.f,0.f,0.f};
            #pragma unroll
            for (int ks = 0; ks < 2; ++ks) {
                short8 Bh = *(const short8*)(sm + LDS_PR + ((0*6+dof)*16 + b)*144 + (ks*32 + q*8)*2);
                short8 Bl = *(const short8*)(sm + LDS_PR + ((1*6+dof)*16 + b)*144 + (ks*32 + q*8)*2);
                acc = mfma16(aMh[ks], Bh, acc);
                acc = mfma16(aMh[ks], Bl, acc);
                acc = mfma16(aMl[ks], Bh, acc);
            }
            ushort4v wh, wl;
            unsigned short axh[4];
            #pragma unroll
            for (int reg = 0; reg < 4; ++reg) {
                float axn = acc[reg];
                float cl = fminf(bm, fmaxf(-bm, axn));
                float wv = axn + cl;
                unsigned short h = bf16_rne(wv);
                wh[reg] = h;
                wl[reg] = bf16_rne(wv - bf16_f32(h));
                axh[reg] = bf16_rne(axn);
            }
            int off = (rt*16 + q*4)*2;
            *(ushort4v*)(sm + LDS_W0 + ((0*6+dof)*16 + b)*272 + off) = wh;
            *(ushort4v*)(sm + LDS_W0 + ((1*6+dof)*16 + b)*272 + off) = wl;
            axp[m][dof][0] = ((unsigned)axh[1] << 16) | axh[0];
            axp[m][dof][1] = ((unsigned)axh[3] << 16) | axh[2];
        }
        __syncthreads();
        short8 aTh[4], aTl[4];
        #pragma unroll
        for (int ks = 0; ks < 4; ++ks) {
            aTh[ks] = *(const short8*)(MTA + (((((m*4+kt)*4+ks)*2+0)*512) + lane*8));
            aTl[ks] = *(const short8*)(MTA + (((((m*4+kt)*4+ks)*2+1)*512) + lane*8));
        }
        #pragma unroll
        for (int du = 0; du < 3; ++du) {
            int dof = du*2 + dhi;
            f32x4 accH = {0.f,0.f,0.f,0.f};
            #pragma unroll
            for (int ks = 0; ks < 4; ++ks) {
                short8 Bwh = *(const short8*)(sm + LDS_W0 + ((0*6+dof)*16 + b)*272 + (ks*32 + q*8)*2);
                short8 Bwl = *(const short8*)(sm + LDS_W0 + ((1*6+dof)*16 + b)*272 + (ks*32 + q*8)*2);
                accH = mfma16(aTh[ks], Bwh, accH);
                accH = mfma16(aTh[ks], Bwl, accH);
                accH = mfma16(aTl[ks], Bwh, accH);
            }
            #pragma unroll
            for (int reg = 0; reg < 4; ++reg)
                slotF[sb + 12 + du*4 + reg] += accH[reg];
        }
        __syncthreads();
    }

    // ==================== 15 iterations ====================
    for (int it = 0; it < NITER; ++it) {
        // ---- phase A: t = L + hS + c ----
        #pragma unroll
        for (int du = 0; du < 3; ++du) {
            int dof = du*2 + dhi;
            ushort4v hi4, lo4;
            #pragma unroll
            for (int reg = 0; reg < 4; ++reg) {
                float tv = slotF[sb + du*4 + reg] + slotF[sb + 12 + du*4 + reg] + cR[du][reg];
                unsigned short h = bf16_rne(tv);
                hi4[reg] = h;
                lo4[reg] = bf16_rne(tv - bf16_f32(h));
            }
            int off = (kt*16 + q*4)*2;
            *(ushort4v*)(sm + LDS_LN + ((0*6+dof)*16 + b)*144 + off) = hi4;
            *(ushort4v*)(sm + LDS_LN + ((1*6+dof)*16 + b)*144 + off) = lo4;
        }
        __syncthreads();

        // ---- phase B: primal ----
        {
            short8 aWh[2], aWl[2];
            #pragma unroll
            for (int js = 0; js < 2; ++js) {
                aWh[js] = *(const short8*)(WVA + (((kt*2+js)*2+0)*512 + lane*8));
                aWl[js] = *(const short8*)(WVA + (((kt*2+js)*2+1)*512 + lane*8));
            }
            float cdq = 0.f;
            #pragma unroll
            for (int du = 0; du < 3; ++du) {
                int dof = du*2 + dhi;
                f32x4 acc = {0.f,0.f,0.f,0.f};
                #pragma unroll
                for (int js = 0; js < 2; ++js) {
                    short8 Bh = *(const short8*)(sm + LDS_LN + ((0*6+dof)*16 + b)*144 + (js*32 + q*8)*2);
                    short8 Bl = *(const short8*)(sm + LDS_LN + ((1*6+dof)*16 + b)*144 + (js*32 + q*8)*2);
                    acc = mfma16(aWh[js], Bh, acc);
                    acc = mfma16(aWh[js], Bl, acc);
                    acc = mfma16(aWl[js], Bh, acc);
                }
                ushort4v hi4, lo4;
                #pragma unroll
                for (int reg = 0; reg < 4; ++reg) {
                    float pr = acc[reg] + pbq[du][reg];
                    float cd = pr - cR[du][reg];
                    cdq += cd * cd;
                    cR[du][reg] = pr;
                    unsigned short h = bf16_rne(pr);
                    hi4[reg] = h;
                    lo4[reg] = bf16_rne(pr - bf16_f32(h));
                }
                int off = (kt*16 + q*4)*2;
                *(ushort4v*)(sm + LDS_PR + ((0*6+dof)*16 + b)*144 + off) = hi4;
                *(ushort4v*)(sm + LDS_PR + ((1*6+dof)*16 + b)*144 + off) = lo4;
            }
            cdq += __shfl_xor(cdq, 16, 64);
            cdq += __shfl_xor(cdq, 32, 64);
            if (lane < 16) atomicAdd(&waccF[9*16 + b], cdq);
        }
        __syncthreads();

        // ---- reset own hS slots (same-thread, program order suffices) ----
        #pragma unroll
        for (int i = 0; i < 12; ++i) slotF[sb + 12 + i] = 0.f;

        // ---- phases C/D (dynamic m loop — keep dynamic) ----
        for (int m = 0; m < 3; ++m) {
            const float bm = (m==0) ? 0.8f : ((m==1) ? 1.8f : PI_F);
            short8 aMh[2], aMl[2];
            #pragma unroll
            for (int ks = 0; ks < 2; ++ks) {
                aMh[ks] = *(const short8*)(MA + ((((m*8+rt)*2+ks)*2+0)*512 + lane*8));
                aMl[ks] = *(const short8*)(MA + ((((m*8+rt)*2+ks)*2+1)*512 + lane*8));
            }
            float resq = 0.f, sdq = 0.f;
            #pragma unroll
            for (int dof = 0; dof < 6; ++dof) {
                f32x4 acc = {0.f,0.f,0.f,0.f};
                #pragma unroll
                for (int ks = 0; ks < 2; ++ks) {
                    short8 Bh = *(const short8*)(sm + LDS_PR + ((0*6+dof)*16 + b)*144 + (ks*32 + q*8)*2);
                    short8 Bl = *(const short8*)(sm + LDS_PR + ((1*6+dof)*16 + b)*144 + (ks*32 + q*8)*2);
                    acc = mfma16(aMh[ks], Bh, acc);
                    acc = mfma16(aMh[ks], Bl, acc);
                    acc = mfma16(aMl[ks], Bh, acc);
                }
                ushort4v dh, wh, wl;
                unsigned short axh[4];
                unsigned p0 = axp[m][dof][0], p1 = axp[m][dof][1];
                #pragma unroll
                for (int reg = 0; reg < 4; ++reg) {
                    float axn = acc[reg];
                    float axo = bf16_f32((unsigned short)((reg < 2 ? p0 >> (16*reg) : p1 >> (16*(reg-2))) & 0xFFFF));
                    float cl = fminf(bm, fmaxf(-bm, axn));
                    float d  = axn - cl;
                    float wv = axn + cl;
                    resq += d * d;
                    float d1 = fmaxf(0.f, bm - axn) - fmaxf(0.f, bm - axo);
                    float d2 = fmaxf(0.f, bm + axn) - fmaxf(0.f, bm + axo);
                    sdq += d1*d1 + d2*d2;
                    dh[reg] = bf16_rne(d);
                    unsigned short h = bf16_rne(wv);
                    wh[reg] = h;
                    wl[reg] = bf16_rne(wv - bf16_f32(h));
                    axh[reg] = bf16_rne(axn);
                }
                int off = (rt*16 + q*4)*2;
                *(ushort4v*)(sm + LDS_D0 + (dof*16 + b)*272 + off) = dh;
                *(ushort4v*)(sm + LDS_W0 + ((0*6+dof)*16 + b)*272 + off) = wh;
                *(ushort4v*)(sm + LDS_W0 + ((1*6+dof)*16 + b)*272 + off) = wl;
                axp[m][dof][0] = ((unsigned)axh[1] << 16) | axh[0];
                axp[m][dof][1] = ((unsigned)axh[3] << 16) | axh[2];
            }
            resq += __shfl_xor(resq, 16, 64); resq += __shfl_xor(resq, 32, 64);
            sdq  += __shfl_xor(sdq, 16, 64);  sdq  += __shfl_xor(sdq, 32, 64);
            if (lane < 16) {
                atomicAdd(&waccF[m*16 + b], resq);
                atomicAdd(&waccF[(3+m)*16 + b], sdq);
            }
            __syncthreads();

            short8 aTh[4], aTl[4];
            #pragma unroll
            for (int ks = 0; ks < 4; ++ks) {
                aTh[ks] = *(const short8*)(MTA + (((((m*4+kt)*4+ks)*2+0)*512) + lane*8));
                aTl[ks] = *(const short8*)(MTA + (((((m*4+kt)*4+ks)*2+1)*512) + lane*8));
            }
            float ldq = 0.f;
            #pragma unroll
            for (int du = 0; du < 3; ++du) {
                int dof = du*2 + dhi;
                f32x4 accD = {0.f,0.f,0.f,0.f};
                f32x4 accH = {0.f,0.f,0.f,0.f};
                #pragma unroll
                for (int ks = 0; ks < 4; ++ks) {
                    short8 Bdh = *(const short8*)(sm + LDS_D0 + (dof*16 + b)*272 + (ks*32 + q*8)*2);
                    short8 Bwh = *(const short8*)(sm + LDS_W0 + ((0*6+dof)*16 + b)*272 + (ks*32 + q*8)*2);
                    short8 Bwl = *(const short8*)(sm + LDS_W0 + ((1*6+dof)*16 + b)*272 + (ks*32 + q*8)*2);
                    accD = mfma16(aTh[ks], Bdh, accD);
                    accD = mfma16(aTl[ks], Bdh, accD);
                    accH = mfma16(aTh[ks], Bwh, accH);
                    accH = mfma16(aTh[ks], Bwl, accH);
                    accH = mfma16(aTl[ks], Bwh, accH);
                }
                #pragma unroll
                for (int reg = 0; reg < 4; ++reg) {
                    float delta = accD[reg];
                    slotF[sb + du*4 + reg] -= delta;           // L update (own LDS slot)
                    ldq += delta * delta;
                    slotF[sb + 12 + du*4 + reg] += accH[reg];  // hS accumulate
                }
            }
            ldq += __shfl_xor(ldq, 16, 64); ldq += __shfl_xor(ldq, 32, 64);
            if (lane < 16) atomicAdd(&waccF[(6+m)*16 + b], ldq);
            __syncthreads();
        }

        if (t < 16) {
            float rp = sqrtf(waccF[0*16+t]) + sqrtf(waccF[1*16+t]) + sqrtf(waccF[2*16+t]);
            float fp = sqrtf(waccF[3*16+t]) + sqrtf(waccF[4*16+t]) + sqrtf(waccF[5*16+t])
                     + sqrtf(waccF[6*16+t]) + sqrtf(waccF[7*16+t]) + sqrtf(waccF[8*16+t])
                     + sqrtf(waccF[9*16+t]);
            accN[t]      += fp;
            accN[16 + t] += rp;
            #pragma unroll
            for (int n = 0; n < 10; ++n) waccF[n*16+t] = 0.f;
        }
        __syncthreads();
    }

    #pragma unroll
    for (int du = 0; du < 3; ++du) {
        int dof = du*2 + dhi;
        #pragma unroll
        for (int reg = 0; reg < 4; ++reg) {
            int k = kt*16 + q*4 + reg;
            outG[(size_t)(bbase+b)*384 + dof*64 + k] = cR[du][reg];
        }
    }
    if (t < 16) {
        outG[(size_t)NBATCH*384 + bbase + t]          = accN[t] / 15.f;
        outG[(size_t)NBATCH*384 + NBATCH + bbase + t] = accN[16 + t] / 15.f;
    }
}

extern "C" void kernel_launch(void* const* d_in, const int* in_sizes, int n_in,
                              void* d_out, int out_size, void* d_ws, size_t ws_size,
                              hipStream_t stream) {
    const float* P     = (const float*)d_in[0];
    const float* Pdot  = (const float*)d_in[1];
    const float* Pddot = (const float*)d_in[2];
    const float* lam   = (const float*)d_in[3];
    const float* csamp = (const float*)d_in[4];
    const float* beq   = (const float*)d_in[5];
    float* out = (float*)d_out;

    float* QdG  = (float*)d_ws;            // 4416 floats; rows 64..68 become Winv rows
    float* WinvG = (float*)d_ws;           // same slot (admm reads offsets 4096..4415 only)
    unsigned short* MA  = (unsigned short*)((char*)d_ws + WS_FRAG_OFF);
    unsigned short* MTA = MA + 49152;
    unsigned short* WVA = MTA + 49152;

    hipLaunchKernelGGL(pack_and_build, dim3(402), dim3(256), 0, stream, P, Pdot, Pddot, QdG, MA, MTA);
    hipLaunchKernelGGL(invert_qd, dim3(1), dim3(256), 0, stream, QdG, WinvG, WVA);

    hipFuncSetAttribute((const void*)admm_kernel,
                        hipFuncAttributeMaxDynamicSharedMemorySize, LDS_TOTAL);
    hipLaunchKernelGGL(admm_kernel, dim3(NBATCH/NBPB), dim3(TPB), LDS_TOTAL, stream,
                       lam, csamp, beq, WinvG, MA, MTA, WVA, out);
}

// Round 16
// 429.224 us; speedup vs baseline: 10.8697x; 1.0542x over previous
//
#include <hip/hip_runtime.h>
#include <math.h>

#define NITER 15
#define TPB 512
#define NBATCH 4096
#define NBPB 16
#define PI_F 3.14159265358979323846f

typedef __attribute__((ext_vector_type(8))) short short8;
typedef __attribute__((ext_vector_type(4))) float f32x4;
typedef __attribute__((ext_vector_type(4))) unsigned short ushort4v;

// ---------------- LDS layout (bytes) ----------------
#define LDS_D0   0
#define LDS_LN   0
#define LDS_PR   27648
#define LDS_W0   55296
#define LDS_WACC 107520
#define LDS_ACCN 108160
#define LDS_SLOT 108288
#define SLOT_STRIDE 25
#define LDS_TOTAL (108288 + 512*SLOT_STRIDE*4)   // 159488 <= 163840

// ---------------- ws layout ----------------
#define WS_FRAG_OFF 17920

__device__ __forceinline__ unsigned short bf16_rne(float x) {
    unsigned u = __float_as_uint(x);
    unsigned r = (u + 0x7FFFu + ((u >> 16) & 1u)) >> 16;
    return (unsigned short)r;
}
__device__ __forceinline__ float bf16_f32(unsigned short h) {
    return __uint_as_float(((unsigned)h) << 16);
}

// ===================== K1: pack MA/MTA (blocks 0..383) + build Qd (blocks 384..401) ==
__global__ void pack_and_build(const float* __restrict__ P, const float* __restrict__ Pd,
                               const float* __restrict__ Pdd, float* __restrict__ QdG,
                               unsigned short* __restrict__ MA, unsigned short* __restrict__ MTA) {
    if (blockIdx.x < 384) {
        int tid = blockIdx.x*256 + threadIdx.x;
        if (tid < 49152) {                       // MA [m][rt8][ks2][pl2][lane][8] ; A = M[r][k]
            int j = tid & 7, lane = (tid>>3)&63, pl = (tid>>9)&1, ks = (tid>>10)&1, rt = (tid>>11)&7, m = tid>>14;
            const float* src = (m==0) ? Pd : ((m==1) ? Pdd : P);
            int r = rt*16 + (lane&15);
            int k = ks*32 + (lane>>4)*8 + j;
            float x = src[r*64+k];
            unsigned short hi = bf16_rne(x);
            MA[tid] = pl ? bf16_rne(x - bf16_f32(hi)) : hi;
        } else {                                 // MTA [m][kt4][ks4][pl2][lane][8] ; A = M^T[k][r]
            int t2 = tid - 49152;
            int j = t2 & 7, lane = (t2>>3)&63, pl = (t2>>9)&1, ks = (t2>>10)&3, kt = (t2>>12)&3, m = t2>>14;
            const float* src = (m==0) ? Pd : ((m==1) ? Pdd : P);
            int k = kt*16 + (lane&15);
            int r = ks*32 + (lane>>4)*8 + j;
            float x = src[r*64+k];
            unsigned short hi = bf16_rne(x);
            MTA[t2] = pl ? bf16_rne(x - bf16_f32(hi)) : hi;
        }
    } else {
        int idx = (blockIdx.x - 384)*256 + threadIdx.x;
        if (idx < 4096) {
            int i = idx >> 6, j = idx & 63;
            float acc = 0.f;
            for (int r = 0; r < 128; ++r) {
                acc += Pd[r*64+i]*Pd[r*64+j];
                acc += Pdd[r*64+i]*Pdd[r*64+j];
                acc += P[r*64+i]*P[r*64+j];
            }
            QdG[idx] = (i == j ? 1.f : 0.f) + 2.f*acc;
        } else if (idx < 4416) {
            int r2 = idx - 4096;
            int e = r2 >> 6, k = r2 & 63;
            float v = (e == 0) ? P[k] : (e == 1) ? Pd[k] : (e == 2) ? Pdd[k]
                    : (e == 3) ? Pd[127*64+k] : Pdd[127*64+k];
            QdG[idx] = v;
        }
    }
}

// ===================== K2: invert Qd — 256-thread float4 elimination, 2 barriers/pivot ==
// Same pivot selection (first-max butterfly) and same per-cell arithmetic as R15
// -> bit-identical Winv/WVA. Row stride padded to 144 floats (9 aligned float4/row);
// pad cols 140..143 stay zero (rank-1 update is per-cell, never feeds real cols).
__global__ void invert_qd(const float* __restrict__ QdG, float* __restrict__ Winv,
                          unsigned short* __restrict__ WVA) {
    __shared__ float aug[69][144];
    __shared__ float prow[144];
    __shared__ float srow[144];
    const int t = threadIdx.x;  // 256
    const int lane = t & 63;

    for (int idx = t; idx < 69*144; idx += 256) ((float*)aug)[idx] = 0.f;
    __syncthreads();
    for (int idx = t; idx < 4096; idx += 256) aug[idx >> 6][idx & 63] = QdG[idx];
    for (int idx = t; idx < 320; idx += 256) {
        int e = idx >> 6, k = idx & 63;
        float v = QdG[4096 + idx];
        aug[k][64+e] = v;
        aug[64+e][k] = v;
    }
    for (int i = t; i < 69; i += 256) aug[i][69+i] = 1.f;
    __syncthreads();

    const int tr = t >> 2;        // 0..63 -> handles rows tr and tr+64 (if <69)
    const int tc = t & 3;         // col quarter: cols [tc*36, tc*36+36)
    for (int p = 0; p < 69; ++p) {
        // redundant per-wave argmax: every lane ends with identical (bv, bi)
        float bv = -1.f; int bi = p;
        for (int r = p + lane; r < 69; r += 64) {
            float a = fabsf(aug[r][p]);
            if (a > bv) { bv = a; bi = r; }
        }
        #pragma unroll
        for (int off = 32; off > 0; off >>= 1) {
            float ov = __shfl_xor(bv, off, 64);
            int   oi = __shfl_xor(bi, off, 64);
            if (ov > bv || (ov == bv && oi < bi)) { bv = ov; bi = oi; }
        }
        const int pv = bi;
        const float inv = 1.f / aug[pv][p];
        const float fi0 = aug[tr][p];                           // pre-barrier snapshot
        const float fi1 = (tr + 64 < 69) ? aug[tr + 64][p] : 0.f;
        if (t < 144) {
            prow[t] = aug[pv][t] * inv;
            srow[t] = aug[p][t];
        }
        __syncthreads();          // all reads done before writes
        const int cb = tc * 36;
        #pragma unroll
        for (int h = 0; h < 2; ++h) {
            const int row = tr + h*64;
            const float fi = h ? fi1 : fi0;
            if (row < 69) {
                if (row == p) {
                    #pragma unroll
                    for (int j4 = 0; j4 < 9; ++j4)
                        *(float4*)(&aug[p][cb + j4*4]) = *(const float4*)(&prow[cb + j4*4]);
                } else if (row == pv) {
                    const float f2 = srow[p];
                    #pragma unroll
                    for (int j4 = 0; j4 < 9; ++j4) {
                        float4 pvv = *(const float4*)(&prow[cb + j4*4]);
                        float4 sv  = *(const float4*)(&srow[cb + j4*4]);
                        sv.x -= f2*pvv.x; sv.y -= f2*pvv.y;
                        sv.z -= f2*pvv.z; sv.w -= f2*pvv.w;
                        *(float4*)(&aug[pv][cb + j4*4]) = sv;
                    }
                } else {
                    #pragma unroll
                    for (int j4 = 0; j4 < 9; ++j4) {
                        float4 pvv = *(const float4*)(&prow[cb + j4*4]);
                        float4 av = *(float4*)(&aug[row][cb + j4*4]);
                        av.x -= fi*pvv.x; av.y -= fi*pvv.y;
                        av.z -= fi*pvv.z; av.w -= fi*pvv.w;
                        *(float4*)(&aug[row][cb + j4*4]) = av;
                    }
                }
            }
        }
        __syncthreads();          // elimination done before next argmax
    }

    // tail: Winv rows 64..68 (for admm pbq) + WVA fragments straight from LDS
    for (int idx = t; idx < 320; idx += 256)
        Winv[4096 + idx] = aug[64 + (idx >> 6)][69 + (idx & 63)];
    for (int idx = t; idx < 8192; idx += 256) {
        int j = idx & 7, ln = (idx>>3)&63, pl = (idx>>9)&1, js = (idx>>10)&1, kt2 = idx>>11;
        int kp = kt2*16 + (ln&15);
        int jj = js*32 + (ln>>4)*8 + j;
        float x = aug[jj][69 + kp];
        unsigned short hi = bf16_rne(x);
        WVA[idx] = pl ? bf16_rne(x - bf16_f32(hi)) : hi;
    }
}

// ===================== main ADMM kernel — R13 VERBATIM (green, do not perturb) ==
// State residency rule (R4-R14): persistent accumulators must NOT be register-
// promoted; no unrolling of the m loops; no inline asm in this kernel. L and hS
// live in per-thread LDS slots; axp in scratch (L2-resident).
__device__ __forceinline__ f32x4 mfma16(short8 a, short8 b, f32x4 c) {
    return __builtin_amdgcn_mfma_f32_16x16x32_bf16(a, b, c, 0, 0, 0);
}

__global__ void __launch_bounds__(TPB, 2)
admm_kernel(const float* __restrict__ lamG, const float* __restrict__ cG,
            const float* __restrict__ beqG, const float* __restrict__ WinvG,
            const unsigned short* __restrict__ MA, const unsigned short* __restrict__ MTA,
            const unsigned short* __restrict__ WVA, float* __restrict__ outG) {
    extern __shared__ char sm[];
    float* waccF = (float*)(sm + LDS_WACC);   // [10][16]
    float* accN  = (float*)(sm + LDS_ACCN);   // [2][16]
    float* slotF = (float*)(sm + LDS_SLOT);   // [512][25]: L +0..11, hS +12..23

    const int t = threadIdx.x;
    const int lane = t & 63;
    const int w = t >> 6;
    const int b = lane & 15;
    const int q = lane >> 4;
    const int kt = w & 3;
    const int dhi = w >> 2;
    const int rt = w;
    const int bbase = blockIdx.x * NBPB;
    const int sb = t * SLOT_STRIDE;

    float cR[3][4];
    float pbq[3][4];
    unsigned axp[3][6][2];   // prev ax, bf16-packed; dynamic m -> scratch (L2-resident)

    for (int i = t; i < 160 + 32; i += TPB) ((float*)(sm + LDS_WACC))[i] = 0.f;
    #pragma unroll
    for (int i = 0; i < 12; ++i) slotF[sb + 12 + i] = 0.f;   // hS = 0

    #pragma unroll
    for (int du = 0; du < 3; ++du) {
        int dof = du*2 + dhi;
        #pragma unroll
        for (int reg = 0; reg < 4; ++reg) {
            int k = kt*16 + q*4 + reg;
            cR[du][reg] = cG[(size_t)(bbase+b)*384 + dof*64 + k];
            float ls = 0.f;
            #pragma unroll
            for (int m = 0; m < 3; ++m)
                ls += lamG[(size_t)(bbase+b)*1152 + m*384 + dof*64 + k];
            slotF[sb + du*4 + reg] = ls;                      // L init
            float s = 0.f;
            #pragma unroll
            for (int e = 0; e < 5; ++e)
                s += WinvG[(64+e)*64 + k] * beqG[(size_t)(bbase+b)*30 + dof*5 + e];
            pbq[du][reg] = s;
        }
    }

    #pragma unroll
    for (int du = 0; du < 3; ++du) {
        int dof = du*2 + dhi;
        ushort4v hi4, lo4;
        #pragma unroll
        for (int reg = 0; reg < 4; ++reg) {
            unsigned short h = bf16_rne(cR[du][reg]);
            hi4[reg] = h;
            lo4[reg] = bf16_rne(cR[du][reg] - bf16_f32(h));
        }
        int off = (kt*16 + q*4)*2;
        *(ushort4v*)(sm + LDS_PR + ((0*6+dof)*16 + b)*144 + off) = hi4;
        *(ushort4v*)(sm + LDS_PR + ((1*6+dof)*16 + b)*144 + off) = lo4;
    }
    __syncthreads();

    // ---- prologue (dynamic m loop — keep dynamic; register-promoted state miscompiles) ----
    for (int m = 0; m < 3; ++m) {
        const float bm = (m==0) ? 0.8f : ((m==1) ? 1.8f : PI_F);
        short8 aMh[2], aMl[2];
        #pragma unroll
        for (int ks = 0; ks < 2; ++ks) {
            aMh[ks] = *(const short8*)(MA + ((((m*8+rt)*2+ks)*2+0)*512 + lane*8));
            aMl[ks] = *(const short8*)(MA + ((((m*8+rt)*2+ks)*2+1)*512 + lane*8));
        }
        #pragma unroll
        for (int dof = 0; dof < 6; ++dof) {
            f32x4 acc = {0.f,0.f,0.f,0.f};
            #pragma unroll
            for (int ks = 0; ks < 2; ++ks) {
                short8 Bh = *(const short8*)(sm + LDS_PR + ((0*6+dof)*16 + b)*144 + (ks*32 + q*8)*2);
                short8 Bl = *(const short8*)(sm + LDS_PR + ((1*6+dof)*16 + b)*144 + (ks*32 + q*8)*2);
                acc = mfma16(aMh[ks], Bh, acc);
                acc = mfma16(aMh[ks], Bl, acc);
                acc = mfma16(aMl[ks], Bh, acc);
            }
            ushort4v wh, wl;
            unsigned short axh[4];
            #pragma unroll
            for (int reg = 0; reg < 4; ++reg) {
                float axn = acc[reg];
                float cl = fminf(bm, fmaxf(-bm, axn));
                float wv = axn + cl;
                unsigned short h = bf16_rne(wv);
                wh[reg] = h;
                wl[reg] = bf16_rne(wv - bf16_f32(h));
                axh[reg] = bf16_rne(axn);
            }
            int off = (rt*16 + q*4)*2;
            *(ushort4v*)(sm + LDS_W0 + ((0*6+dof)*16 + b)*272 + off) = wh;
            *(ushort4v*)(sm + LDS_W0 + ((1*6+dof)*16 + b)*272 + off) = wl;
            axp[m][dof][0] = ((unsigned)axh[1] << 16) | axh[0];
            axp[m][dof][1] = ((unsigned)axh[3] << 16) | axh[2];
        }
        __syncthreads();
        short8 aTh[4], aTl[4];
        #pragma unroll
        for (int ks = 0; ks < 4; ++ks) {
            aTh[ks] = *(const short8*)(MTA + (((((m*4+kt)*4+ks)*2+0)*512) + lane*8));
            aTl[ks] = *(const short8*)(MTA + (((((m*4+kt)*4+ks)*2+1)*512) + lane*8));
        }
        #pragma unroll
        for (int du = 0; du < 3; ++du) {
            int dof = du*2 + dhi;
            f32x4 accH = {0.f,0.f,0.f,0.f};
            #pragma unroll
            for (int ks = 0; ks < 4; ++ks) {
                short8 Bwh = *(const short8*)(sm + LDS_W0 + ((0*6+dof)*16 + b)*272 + (ks*32 + q*8)*2);
                short8 Bwl = *(const short8*)(sm + LDS_W0 + ((1*6+dof)*16 + b)*272 + (ks*32 + q*8)*2);
                accH = mfma16(aTh[ks], Bwh, accH);
                accH = mfma16(aTh[ks], Bwl, accH);
                accH = mfma16(aTl[ks], Bwh, accH);
            }
            #pragma unroll
            for (int reg = 0; reg < 4; ++reg)
                slotF[sb + 12 + du*4 + reg] += accH[reg];
        }
        __syncthreads();
    }

    // ==================== 15 iterations ====================
    for (int it = 0; it < NITER; ++it) {
        // ---- phase A: t = L + hS + c ----
        #pragma unroll
        for (int du = 0; du < 3; ++du) {
            int dof = du*2 + dhi;
            ushort4v hi4, lo4;
            #pragma unroll
            for (int reg = 0; reg < 4; ++reg) {
                float tv = slotF[sb + du*4 + reg] + slotF[sb + 12 + du*4 + reg] + cR[du][reg];
                unsigned short h = bf16_rne(tv);
                hi4[reg] = h;
                lo4[reg] = bf16_rne(tv - bf16_f32(h));
            }
            int off = (kt*16 + q*4)*2;
            *(ushort4v*)(sm + LDS_LN + ((0*6+dof)*16 + b)*144 + off) = hi4;
            *(ushort4v*)(sm + LDS_LN + ((1*6+dof)*16 + b)*144 + off) = lo4;
        }
        __syncthreads();

        // ---- phase B: primal ----
        {
            short8 aWh[2], aWl[2];
            #pragma unroll
            for (int js = 0; js < 2; ++js) {
                aWh[js] = *(const short8*)(WVA + (((kt*2+js)*2+0)*512 + lane*8));
                aWl[js] = *(const short8*)(WVA + (((kt*2+js)*2+1)*512 + lane*8));
            }
            float cdq = 0.f;
            #pragma unroll
            for (int du = 0; du < 3; ++du) {
                int dof = du*2 + dhi;
                f32x4 acc = {0.f,0.f,0.f,0.f};
                #pragma unroll
                for (int js = 0; js < 2; ++js) {
                    short8 Bh = *(const short8*)(sm + LDS_LN + ((0*6+dof)*16 + b)*144 + (js*32 + q*8)*2);
                    short8 Bl = *(const short8*)(sm + LDS_LN + ((1*6+dof)*16 + b)*144 + (js*32 + q*8)*2);
                    acc = mfma16(aWh[js], Bh, acc);
                    acc = mfma16(aWh[js], Bl, acc);
                    acc = mfma16(aWl[js], Bh, acc);
                }
                ushort4v hi4, lo4;
                #pragma unroll
                for (int reg = 0; reg < 4; ++reg) {
                    float pr = acc[reg] + pbq[du][reg];
                    float cd = pr - cR[du][reg];
                    cdq += cd * cd;
                    cR[du][reg] = pr;
                    unsigned short h = bf16_rne(pr);
                    hi4[reg] = h;
                    lo4[reg] = bf16_rne(pr - bf16_f32(h));
                }
                int off = (kt*16 + q*4)*2;
                *(ushort4v*)(sm + LDS_PR + ((0*6+dof)*16 + b)*144 + off) = hi4;
                *(ushort4v*)(sm + LDS_PR + ((1*6+dof)*16 + b)*144 + off) = lo4;
            }
            cdq += __shfl_xor(cdq, 16, 64);
            cdq += __shfl_xor(cdq, 32, 64);
            if (lane < 16) atomicAdd(&waccF[9*16 + b], cdq);
        }
        __syncthreads();

        // ---- reset own hS slots (same-thread, program order suffices) ----
        #pragma unroll
        for (int i = 0; i < 12; ++i) slotF[sb + 12 + i] = 0.f;

        // ---- phases C/D (dynamic m loop — keep dynamic) ----
        for (int m = 0; m < 3; ++m) {
            const float bm = (m==0) ? 0.8f : ((m==1) ? 1.8f : PI_F);
            short8 aMh[2], aMl[2];
            #pragma unroll
            for (int ks = 0; ks < 2; ++ks) {
                aMh[ks] = *(const short8*)(MA + ((((m*8+rt)*2+ks)*2+0)*512 + lane*8));
                aMl[ks] = *(const short8*)(MA + ((((m*8+rt)*2+ks)*2+1)*512 + lane*8));
            }
            float resq = 0.f, sdq = 0.f;
            #pragma unroll
            for (int dof = 0; dof < 6; ++dof) {
                f32x4 acc = {0.f,0.f,0.f,0.f};
                #pragma unroll
                for (int ks = 0; ks < 2; ++ks) {
                    short8 Bh = *(const short8*)(sm + LDS_PR + ((0*6+dof)*16 + b)*144 + (ks*32 + q*8)*2);
                    short8 Bl = *(const short8*)(sm + LDS_PR + ((1*6+dof)*16 + b)*144 + (ks*32 + q*8)*2);
                    acc = mfma16(aMh[ks], Bh, acc);
                    acc = mfma16(aMh[ks], Bl, acc);
                    acc = mfma16(aMl[ks], Bh, acc);
                }
                ushort4v dh, wh, wl;
                unsigned short axh[4];
                unsigned p0 = axp[m][dof][0], p1 = axp[m][dof][1];
                #pragma unroll
                for (int reg = 0; reg < 4; ++reg) {
                    float axn = acc[reg];
                    float axo = bf16_f32((unsigned short)((reg < 2 ? p0 >> (16*reg) : p1 >> (16*(reg-2))) & 0xFFFF));
                    float cl = fminf(bm, fmaxf(-bm, axn));
                    float d  = axn - cl;
                    float wv = axn + cl;
                    resq += d * d;
                    float d1 = fmaxf(0.f, bm - axn) - fmaxf(0.f, bm - axo);
                    float d2 = fmaxf(0.f, bm + axn) - fmaxf(0.f, bm + axo);
                    sdq += d1*d1 + d2*d2;
                    dh[reg] = bf16_rne(d);
                    unsigned short h = bf16_rne(wv);
                    wh[reg] = h;
                    wl[reg] = bf16_rne(wv - bf16_f32(h));
                    axh[reg] = bf16_rne(axn);
                }
                int off = (rt*16 + q*4)*2;
                *(ushort4v*)(sm + LDS_D0 + (dof*16 + b)*272 + off) = dh;
                *(ushort4v*)(sm + LDS_W0 + ((0*6+dof)*16 + b)*272 + off) = wh;
                *(ushort4v*)(sm + LDS_W0 + ((1*6+dof)*16 + b)*272 + off) = wl;
                axp[m][dof][0] = ((unsigned)axh[1] << 16) | axh[0];
                axp[m][dof][1] = ((unsigned)axh[3] << 16) | axh[2];
            }
            resq += __shfl_xor(resq, 16, 64); resq += __shfl_xor(resq, 32, 64);
            sdq  += __shfl_xor(sdq, 16, 64);  sdq  += __shfl_xor(sdq, 32, 64);
            if (lane < 16) {
                atomicAdd(&waccF[m*16 + b], resq);
                atomicAdd(&waccF[(3+m)*16 + b], sdq);
            }
            __syncthreads();

            short8 aTh[4], aTl[4];
            #pragma unroll
            for (int ks = 0; ks < 4; ++ks) {
                aTh[ks] = *(const short8*)(MTA + (((((m*4+kt)*4+ks)*2+0)*512) + lane*8));
                aTl[ks] = *(const short8*)(MTA + (((((m*4+kt)*4+ks)*2+1)*512) + lane*8));
            }
            float ldq = 0.f;
            #pragma unroll
            for (int du = 0; du < 3; ++du) {
                int dof = du*2 + dhi;
                f32x4 accD = {0.f,0.f,0.f,0.f};
                f32x4 accH = {0.f,0.f,0.f,0.f};
                #pragma unroll
                for (int ks = 0; ks < 4; ++ks) {
                    short8 Bdh = *(const short8*)(sm + LDS_D0 + (dof*16 + b)*272 + (ks*32 + q*8)*2);
                    short8 Bwh = *(const short8*)(sm + LDS_W0 + ((0*6+dof)*16 + b)*272 + (ks*32 + q*8)*2);
                    short8 Bwl = *(const short8*)(sm + LDS_W0 + ((1*6+dof)*16 + b)*272 + (ks*32 + q*8)*2);
                    accD = mfma16(aTh[ks], Bdh, accD);
                    accD = mfma16(aTl[ks], Bdh, accD);
                    accH = mfma16(aTh[ks], Bwh, accH);
                    accH = mfma16(aTh[ks], Bwl, accH);
                    accH = mfma16(aTl[ks], Bwh, accH);
                }
                #pragma unroll
                for (int reg = 0; reg < 4; ++reg) {
                    float delta = accD[reg];
                    slotF[sb + du*4 + reg] -= delta;           // L update (own LDS slot)
                    ldq += delta * delta;
                    slotF[sb + 12 + du*4 + reg] += accH[reg];  // hS accumulate
                }
            }
            ldq += __shfl_xor(ldq, 16, 64); ldq += __shfl_xor(ldq, 32, 64);
            if (lane < 16) atomicAdd(&waccF[(6+m)*16 + b], ldq);
            __syncthreads();
        }

        if (t < 16) {
            float rp = sqrtf(waccF[0*16+t]) + sqrtf(waccF[1*16+t]) + sqrtf(waccF[2*16+t]);
            float fp = sqrtf(waccF[3*16+t]) + sqrtf(waccF[4*16+t]) + sqrtf(waccF[5*16+t])
                     + sqrtf(waccF[6*16+t]) + sqrtf(waccF[7*16+t]) + sqrtf(waccF[8*16+t])
                     + sqrtf(waccF[9*16+t]);
            accN[t]      += fp;
            accN[16 + t] += rp;
            #pragma unroll
            for (int n = 0; n < 10; ++n) waccF[n*16+t] = 0.f;
        }
        __syncthreads();
    }

    #pragma unroll
    for (int du = 0; du < 3; ++du) {
        int dof = du*2 + dhi;
        #pragma unroll
        for (int reg = 0; reg < 4; ++reg) {
            int k = kt*16 + q*4 + reg;
            outG[(size_t)(bbase+b)*384 + dof*64 + k] = cR[du][reg];
        }
    }
    if (t < 16) {
        outG[(size_t)NBATCH*384 + bbase + t]          = accN[t] / 15.f;
        outG[(size_t)NBATCH*384 + NBATCH + bbase + t] = accN[16 + t] / 15.f;
    }
}

extern "C" void kernel_launch(void* const* d_in, const int* in_sizes, int n_in,
                              void* d_out, int out_size, void* d_ws, size_t ws_size,
                              hipStream_t stream) {
    const float* P     = (const float*)d_in[0];
    const float* Pdot  = (const float*)d_in[1];
    const float* Pddot = (const float*)d_in[2];
    const float* lam   = (const float*)d_in[3];
    const float* csamp = (const float*)d_in[4];
    const float* beq   = (const float*)d_in[5];
    float* out = (float*)d_out;

    float* QdG  = (float*)d_ws;            // 4416 floats; rows 64..68 become Winv rows
    float* WinvG = (float*)d_ws;           // same slot (admm reads offsets 4096..4415 only)
    unsigned short* MA  = (unsigned short*)((char*)d_ws + WS_FRAG_OFF);
    unsigned short* MTA = MA + 49152;
    unsigned short* WVA = MTA + 49152;

    hipLaunchKernelGGL(pack_and_build, dim3(402), dim3(256), 0, stream, P, Pdot, Pddot, QdG, MA, MTA);
    hipLaunchKernelGGL(invert_qd, dim3(1), dim3(256), 0, stream, QdG, WinvG, WVA);

    hipFuncSetAttribute((const void*)admm_kernel,
                        hipFuncAttributeMaxDynamicSharedMemorySize, LDS_TOTAL);
    hipLaunchKernelGGL(admm_kernel, dim3(NBATCH/NBPB), dim3(TPB), LDS_TOTAL, stream,
                       lam, csamp, beq, WinvG, MA, MTA, WVA, out);
}